// Round 2
// baseline (872.406 us; speedup 1.0000x reference)
//
#include <hip/hip_runtime.h>

// N=1, L=512, F=128, C=64, H=12, QK=32, Vd=32, Pq=8, Pv=8
// proj layout per row (2016 cols): [q 0..383][k 384..767][qp 768..1055][kp 1056..1343][v 1344..1727][vp 1728..2015]
#define PCOLS 2016

constexpr float INV_SQRT_QK = 0.17677669529663687f;  // 1/sqrt(32)
constexpr float S3          = 0.57735026918962576f;  // sqrt(1/3)

// ---------------- K1: all projections as one tiled GEMM ----------------
// grid = 8 i-tiles x 21 o-tiles (96 cols each); 256 threads; thread = 8 rows x 3 cols
__global__ __launch_bounds__(256) void k1_gemm(
    const float* __restrict__ x,
    const float* __restrict__ Wq, const float* __restrict__ Wk,
    const float* __restrict__ Wqp, const float* __restrict__ Wkp,
    const float* __restrict__ Wv, const float* __restrict__ Wvp,
    float* __restrict__ proj) {
  int bt = blockIdx.x;            // 0..167
  int it = bt / 21, ot = bt % 21;
  int i0 = it * 64;
  int tid = threadIdx.x;
  int tr = tid >> 5, tc = tid & 31;
  __shared__ float xs[64 * 128];
  for (int idx = tid; idx < 8192; idx += 256) xs[idx] = x[i0 * 128 + idx];
  const float* Wsec; int lofs, width;
  if (ot < 4)       { Wsec = Wq;  lofs = ot * 96;        width = 384; }
  else if (ot < 8)  { Wsec = Wk;  lofs = (ot - 4) * 96;  width = 384; }
  else if (ot < 11) { Wsec = Wqp; lofs = (ot - 8) * 96;  width = 288; }
  else if (ot < 14) { Wsec = Wkp; lofs = (ot - 11) * 96; width = 288; }
  else if (ot < 18) { Wsec = Wv;  lofs = (ot - 14) * 96; width = 384; }
  else              { Wsec = Wvp; lofs = (ot - 18) * 96; width = 288; }
  __syncthreads();
  float acc[8][3];
  #pragma unroll
  for (int r = 0; r < 8; ++r) { acc[r][0] = 0.f; acc[r][1] = 0.f; acc[r][2] = 0.f; }
  const float* wp0 = Wsec + lofs + tc * 3;
  #pragma unroll 4
  for (int f = 0; f < 128; ++f) {
    float w0 = wp0[f * width], w1 = wp0[f * width + 1], w2 = wp0[f * width + 2];
    const float* xr = xs + (tr * 8) * 128 + f;
    #pragma unroll
    for (int r = 0; r < 8; ++r) {
      float xv = xr[r * 128];
      acc[r][0] += xv * w0; acc[r][1] += xv * w1; acc[r][2] += xv * w2;
    }
  }
  int gc = ot * 96 + tc * 3;
  #pragma unroll
  for (int r = 0; r < 8; ++r) {
    float* dst = proj + (size_t)(i0 + tr * 8 + r) * PCOLS + gc;
    dst[0] = acc[r][0]; dst[1] = acc[r][1]; dst[2] = acc[r][2];
  }
}

// ---------------- K1b: rigid transform (l2g) of qp/kp/vp in-place + q2/k2 norms ----------------
__global__ __launch_bounds__(320) void k1b_xform(
    const float* __restrict__ Rg, const float* __restrict__ tg,
    float* __restrict__ proj, float* __restrict__ q2b, float* __restrict__ k2b) {
  int i = blockIdx.x;
  int tid = threadIdx.x;
  __shared__ float Rs[9], ts[3], sq[192];
  if (tid < 9) Rs[tid] = Rg[i * 9 + tid];
  else if (tid < 12) ts[tid - 9] = tg[i * 3 + tid - 9];
  __syncthreads();
  if (tid < 288) {
    int sec = tid / 96;  // 0:qp 1:kp 2:vp
    int base = (sec == 0) ? 768 : (sec == 1) ? 1056 : 1728;
    float* p = proj + (size_t)i * PCOLS + base + (tid % 96) * 3;
    float p0 = p[0], p1 = p[1], p2 = p[2];
    float g0 = Rs[0]*p0 + Rs[1]*p1 + Rs[2]*p2 + ts[0];
    float g1 = Rs[3]*p0 + Rs[4]*p1 + Rs[5]*p2 + ts[1];
    float g2 = Rs[6]*p0 + Rs[7]*p1 + Rs[8]*p2 + ts[2];
    p[0] = g0; p[1] = g1; p[2] = g2;
    if (sec < 2) sq[tid] = g0*g0 + g1*g1 + g2*g2;
  }
  __syncthreads();
  if (tid < 24) {
    int h = tid % 12;
    const float* s = sq + (tid / 12) * 96 + h * 8;
    float a = s[0]+s[1]+s[2]+s[3]+s[4]+s[5]+s[6]+s[7];
    if (tid < 12) q2b[i * 12 + h] = a; else k2b[i * 12 + h] = a;
  }
}

// ---------------- K23: logits + softmax + aggregation, fused per query row ----------------
// 512 threads: logits phase thread = one j; softmax via shfl; alpha kept in LDS (stride 13)
__global__ __launch_bounds__(512) void k23_attn(
    const float* __restrict__ proj, const float* __restrict__ q2b, const float* __restrict__ k2b,
    const float* __restrict__ z, const float* __restrict__ Wpair, const float* __restrict__ sc,
    const float* __restrict__ Rg, const float* __restrict__ tg,
    float* __restrict__ featb) {
  int i = blockIdx.x;
  int tid = threadIdx.x;
  int lane = tid & 63, wv = tid >> 6;
  __shared__ float qs[384], qps[288], q2s[12], coef[12], wp[768];
  __shared__ float Rs[9], ts[3];
  __shared__ float al[512 * 13];   // padded: stride 13 -> conflict-free
  __shared__ float ag[288];
  __shared__ float redbuf[96];     // 8 waves x 12 heads
  const float* prow_i = proj + (size_t)i * PCOLS;
  for (int o = tid; o < 384; o += 512) qs[o] = prow_i[o];
  for (int o = tid; o < 288; o += 512) qps[o] = prow_i[768 + o];
  for (int o = tid; o < 768; o += 512) wp[o] = Wpair[o];
  if (tid < 12) {
    q2s[tid] = q2b[i * 12 + tid];
    coef[tid] = -log1pf(__expf(sc[tid])) * (1.0f / 12.0f);  // -softplus * sqrt(2/(9*Pq))/2
  } else if (tid < 21) Rs[tid - 12] = Rg[i * 9 + tid - 12];
  else if (tid < 24) ts[tid - 21] = tg[i * 3 + tid - 21];
  __syncthreads();

  const int j = tid;
  float lg[12];
  #pragma unroll
  for (int h = 0; h < 12; ++h) lg[h] = 0.f;
  { // pair logits: z[i,j,:] @ Wpair
    const float4* z4 = reinterpret_cast<const float4*>(z + ((size_t)i * 512 + j) * 64);
    for (int c4 = 0; c4 < 16; ++c4) {
      float4 zv = z4[c4];
      const float* w0 = wp + c4 * 48;
      #pragma unroll
      for (int h = 0; h < 12; ++h)
        lg[h] += zv.x * w0[h] + zv.y * w0[12 + h] + zv.z * w0[24 + h] + zv.w * w0[36 + h];
    }
  }
  const float* krow  = proj + (size_t)j * PCOLS + 384;
  const float* kprow = proj + (size_t)j * PCOLS + 1056;
  const float* k2row = k2b + j * 12;
  #pragma unroll
  for (int h = 0; h < 12; ++h) {
    const float4* k4 = reinterpret_cast<const float4*>(krow + h * 32);
    float nd = 0.f;
    #pragma unroll
    for (int d4 = 0; d4 < 8; ++d4) {
      float4 kv = k4[d4];
      nd += qs[h*32+d4*4]*kv.x + qs[h*32+d4*4+1]*kv.y + qs[h*32+d4*4+2]*kv.z + qs[h*32+d4*4+3]*kv.w;
    }
    const float4* kp4 = reinterpret_cast<const float4*>(kprow + h * 24);
    float sp = 0.f;
    #pragma unroll
    for (int d4 = 0; d4 < 6; ++d4) {
      float4 kv = kp4[d4];
      sp += qps[h*24+d4*4]*kv.x + qps[h*24+d4*4+1]*kv.y + qps[h*24+d4*4+2]*kv.z + qps[h*24+d4*4+3]*kv.w;
    }
    float ssd = q2s[h] + k2row[h] - 2.f * sp;
    lg[h] = (nd * INV_SQRT_QK + lg[h] + ssd * coef[h]) * S3;
  }
  // --- softmax over j (= over threads), per h ---
  #pragma unroll
  for (int h = 0; h < 12; ++h) {
    float v = lg[h];
    #pragma unroll
    for (int s = 32; s > 0; s >>= 1) v = fmaxf(v, __shfl_xor(v, s));
    if (lane == 0) redbuf[wv * 12 + h] = v;
  }
  __syncthreads();
  float M[12];
  #pragma unroll
  for (int h = 0; h < 12; ++h) {
    float m = redbuf[h];
    #pragma unroll
    for (int w = 1; w < 8; ++w) m = fmaxf(m, redbuf[w * 12 + h]);
    M[h] = m;
  }
  __syncthreads();  // all reads of redbuf done before reuse
  #pragma unroll
  for (int h = 0; h < 12; ++h) {
    float e = __expf(lg[h] - M[h]);
    lg[h] = e;
    #pragma unroll
    for (int s = 32; s > 0; s >>= 1) e += __shfl_xor(e, s);
    if (lane == 0) redbuf[wv * 12 + h] = e;
  }
  __syncthreads();
  #pragma unroll
  for (int h = 0; h < 12; ++h) {
    float ssum = redbuf[h];
    #pragma unroll
    for (int w = 1; w < 8; ++w) ssum += redbuf[w * 12 + h];
    al[j * 13 + h] = lg[h] / ssum;
  }
  __syncthreads();

  // --- aggregation: thread = output o ---
  float* frow = featb + i * 1440;
  for (int o = tid; o < 1440; o += 512) {
    float acc = 0.f;
    if (o < 768) {                      // feat_p2n: (h,c)
      int h = o >> 6, c = o & 63;
      const float* zp = z + (size_t)i * 512 * 64 + c;
      for (int jj = 0; jj < 512; ++jj) acc += al[jj * 13 + h] * zp[jj * 64];
      frow[o] = acc;
    } else if (o < 1152) {              // feat_node: (h,d)
      int oo = o - 768, h = oo >> 5;
      const float* vp0 = proj + 1344 + oo;
      for (int jj = 0; jj < 512; ++jj) acc += al[jj * 13 + h] * vp0[(size_t)jj * PCOLS];
      frow[o] = acc;
    } else {                            // spatial aggr (global frame)
      int oo = o - 1152, h = oo / 24;
      const float* vpp = proj + 1728 + oo;
      for (int jj = 0; jj < 512; ++jj) acc += al[jj * 13 + h] * vpp[(size_t)jj * PCOLS];
      ag[oo] = acc;
    }
  }
  __syncthreads();
  if (tid < 96) {  // g2l: R^T (aggr - t)
    float d0 = ag[3*tid] - ts[0], d1 = ag[3*tid+1] - ts[1], d2 = ag[3*tid+2] - ts[2];
    frow[1152 + 3*tid + 0] = Rs[0]*d0 + Rs[3]*d1 + Rs[6]*d2;
    frow[1152 + 3*tid + 1] = Rs[1]*d0 + Rs[4]*d1 + Rs[7]*d2;
    frow[1152 + 3*tid + 2] = Rs[2]*d0 + Rs[5]*d1 + Rs[8]*d2;
  }
}

// ---------------- K4: Wo + residual/LN1 + MLP + residual/LN2, one row per block ----------------
// 512 threads = 4 c-split groups x 128 output cols
__global__ __launch_bounds__(512) void k4_mlp(
    const float* __restrict__ featb, const float* __restrict__ x,
    const float* __restrict__ Wo, const float* __restrict__ bo,
    const float* __restrict__ ln1s, const float* __restrict__ ln1o,
    const float* __restrict__ W1, const float* __restrict__ b1,
    const float* __restrict__ W2, const float* __restrict__ b2,
    const float* __restrict__ W3, const float* __restrict__ b3,
    const float* __restrict__ ln2s, const float* __restrict__ ln2o,
    float* __restrict__ out) {
  int i = blockIdx.x;
  int tid = threadIdx.x;
  int q = tid >> 7, col = tid & 127;
  __shared__ float fs[1440];
  __shared__ float part[4][128];
  __shared__ float stg[128];
  for (int o = tid; o < 1440; o += 512) fs[o] = featb[i * 1440 + o];
  __syncthreads();
  float acc = 0.f;
  {
    const float* Wop = Wo + (size_t)(q * 360) * 128 + col;
    const float* fsp = fs + q * 360;
    #pragma unroll 4
    for (int c = 0; c < 360; ++c) acc += fsp[c] * Wop[(size_t)c * 128];
  }
  part[q][col] = acc;
  __syncthreads();
  float y = part[0][col] + part[1][col] + part[2][col] + part[3][col] + bo[col] + x[i * 128 + col];
  if (q == 0) stg[col] = y;
  __syncthreads();
  float s1 = 0.f, s2 = 0.f;
  for (int c = 0; c < 128; ++c) { float v = stg[c]; s1 += v; s2 += v * v; }
  float mu = s1 * (1.f / 128.f);
  float var = s2 * (1.f / 128.f) - mu * mu;
  float x1 = (y - mu) * rsqrtf(var + 1e-5f) * ln1s[col] + ln1o[col];
  __syncthreads();
  if (q == 0) stg[col] = x1;
  __syncthreads();
  // W1
  float a = 0.f;
  { const float* Wp = W1 + (q * 32) * 128 + col;
    #pragma unroll
    for (int c = 0; c < 32; ++c) a += stg[q * 32 + c] * Wp[c * 128]; }
  part[q][col] = a;
  __syncthreads();
  float h1 = fmaxf(part[0][col] + part[1][col] + part[2][col] + part[3][col] + b1[col], 0.f);
  __syncthreads();
  if (q == 0) stg[col] = h1;
  __syncthreads();
  // W2
  a = 0.f;
  { const float* Wp = W2 + (q * 32) * 128 + col;
    #pragma unroll
    for (int c = 0; c < 32; ++c) a += stg[q * 32 + c] * Wp[c * 128]; }
  part[q][col] = a;
  __syncthreads();
  float h2 = fmaxf(part[0][col] + part[1][col] + part[2][col] + part[3][col] + b2[col], 0.f);
  __syncthreads();
  if (q == 0) stg[col] = h2;
  __syncthreads();
  // W3
  a = 0.f;
  { const float* Wp = W3 + (q * 32) * 128 + col;
    #pragma unroll
    for (int c = 0; c < 32; ++c) a += stg[q * 32 + c] * Wp[c * 128]; }
  part[q][col] = a;
  __syncthreads();
  float y2 = x1 + part[0][col] + part[1][col] + part[2][col] + part[3][col] + b3[col];
  __syncthreads();
  if (q == 0) stg[col] = y2;
  __syncthreads();
  s1 = 0.f; s2 = 0.f;
  for (int c = 0; c < 128; ++c) { float v = stg[c]; s1 += v; s2 += v * v; }
  mu = s1 * (1.f / 128.f);
  var = s2 * (1.f / 128.f) - mu * mu;
  if (q == 0) out[i * 128 + col] = (y2 - mu) * rsqrtf(var + 1e-5f) * ln2s[col] + ln2o[col];
}

// ---------------- launch ----------------
extern "C" void kernel_launch(void* const* d_in, const int* in_sizes, int n_in,
                              void* d_out, int out_size, void* d_ws, size_t ws_size,
                              hipStream_t stream) {
  const float* Rg   = (const float*)d_in[0];
  const float* tg   = (const float*)d_in[1];
  const float* x    = (const float*)d_in[2];
  const float* z    = (const float*)d_in[3];
  // d_in[4] = mask (all true) -> no-op
  const float* Wq   = (const float*)d_in[5];
  const float* Wk   = (const float*)d_in[6];
  const float* Wpair= (const float*)d_in[7];
  const float* Wqp  = (const float*)d_in[8];
  const float* Wkp  = (const float*)d_in[9];
  const float* Wv   = (const float*)d_in[10];
  const float* Wvp  = (const float*)d_in[11];
  const float* sc   = (const float*)d_in[12];
  const float* Wo   = (const float*)d_in[13];
  const float* bo   = (const float*)d_in[14];
  const float* ln1s = (const float*)d_in[15];
  const float* ln1o = (const float*)d_in[16];
  const float* W1   = (const float*)d_in[17];
  const float* b1   = (const float*)d_in[18];
  const float* W2   = (const float*)d_in[19];
  const float* b2   = (const float*)d_in[20];
  const float* W3   = (const float*)d_in[21];
  const float* b3   = (const float*)d_in[22];
  const float* ln2s = (const float*)d_in[23];
  const float* ln2o = (const float*)d_in[24];

  float* ws = (float*)d_ws;
  float* proj  = ws;                       // 512*2016 = 1,032,192
  float* q2b   = proj + 512 * 2016;        // 6144
  float* k2b   = q2b + 6144;               // 6144
  float* featb = k2b + 6144;               // 512*1440 = 737,280
  // total ~7.1 MB

  k1_gemm <<<168, 256, 0, stream>>>(x, Wq, Wk, Wqp, Wkp, Wv, Wvp, proj);
  k1b_xform<<<512, 320, 0, stream>>>(Rg, tg, proj, q2b, k2b);
  k23_attn<<<512, 512, 0, stream>>>(proj, q2b, k2b, z, Wpair, sc, Rg, tg, featb);
  k4_mlp  <<<512, 512, 0, stream>>>(featb, x, Wo, bo, ln1s, ln1o,
                                    W1, b1, W2, b2, W3, b3, ln2s, ln2o, (float*)d_out);
}

// Round 3
// 771.736 us; speedup vs baseline: 1.1304x; 1.1304x over previous
//
#include <hip/hip_runtime.h>

// N=1, L=512, F=128, C=64, H=12, QK=32, Vd=32, Pq=8, Pv=8
// proj layout per row (2016 cols): [q 0..383][k 384..767][qp 768..1055][kp 1056..1343][v 1344..1727][vp 1728..2015]
#define PCOLS 2016

constexpr float INV_SQRT_QK = 0.17677669529663687f;  // 1/sqrt(32)
constexpr float S3          = 0.57735026918962576f;  // sqrt(1/3)

#define FMA4(acc, s, b) { acc.x += (s)*(b).x; acc.y += (s)*(b).y; acc.z += (s)*(b).z; acc.w += (s)*(b).w; }

// ---------------- K1: all projections as one tiled GEMM ----------------
__global__ __launch_bounds__(256) void k1_gemm(
    const float* __restrict__ x,
    const float* __restrict__ Wq, const float* __restrict__ Wk,
    const float* __restrict__ Wqp, const float* __restrict__ Wkp,
    const float* __restrict__ Wv, const float* __restrict__ Wvp,
    float* __restrict__ proj) {
  int bt = blockIdx.x;            // 0..167
  int it = bt / 21, ot = bt % 21;
  int i0 = it * 64;
  int tid = threadIdx.x;
  int tr = tid >> 5, tc = tid & 31;
  __shared__ float xs[64 * 128];
  for (int idx = tid; idx < 8192; idx += 256) xs[idx] = x[i0 * 128 + idx];
  const float* Wsec; int lofs, width;
  if (ot < 4)       { Wsec = Wq;  lofs = ot * 96;        width = 384; }
  else if (ot < 8)  { Wsec = Wk;  lofs = (ot - 4) * 96;  width = 384; }
  else if (ot < 11) { Wsec = Wqp; lofs = (ot - 8) * 96;  width = 288; }
  else if (ot < 14) { Wsec = Wkp; lofs = (ot - 11) * 96; width = 288; }
  else if (ot < 18) { Wsec = Wv;  lofs = (ot - 14) * 96; width = 384; }
  else              { Wsec = Wvp; lofs = (ot - 18) * 96; width = 288; }
  __syncthreads();
  float acc[8][3];
  #pragma unroll
  for (int r = 0; r < 8; ++r) { acc[r][0] = 0.f; acc[r][1] = 0.f; acc[r][2] = 0.f; }
  const float* wp0 = Wsec + lofs + tc * 3;
  #pragma unroll 4
  for (int f = 0; f < 128; ++f) {
    float w0 = wp0[f * width], w1 = wp0[f * width + 1], w2 = wp0[f * width + 2];
    const float* xr = xs + (tr * 8) * 128 + f;
    #pragma unroll
    for (int r = 0; r < 8; ++r) {
      float xv = xr[r * 128];
      acc[r][0] += xv * w0; acc[r][1] += xv * w1; acc[r][2] += xv * w2;
    }
  }
  int gc = ot * 96 + tc * 3;
  #pragma unroll
  for (int r = 0; r < 8; ++r) {
    float* dst = proj + (size_t)(i0 + tr * 8 + r) * PCOLS + gc;
    dst[0] = acc[r][0]; dst[1] = acc[r][1]; dst[2] = acc[r][2];
  }
}

// ---------------- K1b: l2g transform of qp/kp/vp in-place + q2/k2 norms ----------------
__global__ __launch_bounds__(320) void k1b_xform(
    const float* __restrict__ Rg, const float* __restrict__ tg,
    float* __restrict__ proj, float* __restrict__ q2b, float* __restrict__ k2b) {
  int i = blockIdx.x;
  int tid = threadIdx.x;
  __shared__ float Rs[9], ts[3], sq[192];
  if (tid < 9) Rs[tid] = Rg[i * 9 + tid];
  else if (tid < 12) ts[tid - 9] = tg[i * 3 + tid - 9];
  __syncthreads();
  if (tid < 288) {
    int sec = tid / 96;  // 0:qp 1:kp 2:vp
    int base = (sec == 0) ? 768 : (sec == 1) ? 1056 : 1728;
    float* p = proj + (size_t)i * PCOLS + base + (tid % 96) * 3;
    float p0 = p[0], p1 = p[1], p2 = p[2];
    float g0 = Rs[0]*p0 + Rs[1]*p1 + Rs[2]*p2 + ts[0];
    float g1 = Rs[3]*p0 + Rs[4]*p1 + Rs[5]*p2 + ts[1];
    float g2 = Rs[6]*p0 + Rs[7]*p1 + Rs[8]*p2 + ts[2];
    p[0] = g0; p[1] = g1; p[2] = g2;
    if (sec < 2) sq[tid] = g0*g0 + g1*g1 + g2*g2;
  }
  __syncthreads();
  if (tid < 24) {
    int h = tid % 12;
    const float* s = sq + (tid / 12) * 96 + h * 8;
    float a = s[0]+s[1]+s[2]+s[3]+s[4]+s[5]+s[6]+s[7];
    if (tid < 12) q2b[i * 12 + h] = a; else k2b[i * 12 + h] = a;
  }
}

// ---------------- K2: logits + softmax -> alpha[i][h][j] (global) ----------------
__global__ __launch_bounds__(512) void k2_logits(
    const float* __restrict__ proj, const float* __restrict__ q2b, const float* __restrict__ k2b,
    const float* __restrict__ z, const float* __restrict__ Wpair, const float* __restrict__ sc,
    float* __restrict__ alphab) {
  int i = blockIdx.x;
  int tid = threadIdx.x;
  int lane = tid & 63, wv = tid >> 6;
  __shared__ float qs[384], qps[288], q2s[12], coef[12], wp[768];
  __shared__ float redbuf[96];
  const float* prow_i = proj + (size_t)i * PCOLS;
  for (int o = tid; o < 384; o += 512) qs[o] = prow_i[o];
  for (int o = tid; o < 288; o += 512) qps[o] = prow_i[768 + o];
  for (int o = tid; o < 768; o += 512) wp[o] = Wpair[o];
  if (tid < 12) {
    q2s[tid] = q2b[i * 12 + tid];
    coef[tid] = -log1pf(__expf(sc[tid])) * (1.0f / 12.0f);  // -softplus * sqrt(2/(9*Pq))/2
  }
  __syncthreads();

  const int j = tid;
  float lg[12];
  #pragma unroll
  for (int h = 0; h < 12; ++h) lg[h] = 0.f;
  { // pair logits: z[i,j,:] @ Wpair
    const float4* z4 = reinterpret_cast<const float4*>(z + ((size_t)i * 512 + j) * 64);
    #pragma unroll 4
    for (int c4 = 0; c4 < 16; ++c4) {
      float4 zv = z4[c4];
      const float* w0 = wp + c4 * 48;
      #pragma unroll
      for (int h = 0; h < 12; ++h)
        lg[h] += zv.x * w0[h] + zv.y * w0[12 + h] + zv.z * w0[24 + h] + zv.w * w0[36 + h];
    }
  }
  const float* krow  = proj + (size_t)j * PCOLS + 384;
  const float* kprow = proj + (size_t)j * PCOLS + 1056;
  const float* k2row = k2b + j * 12;
  #pragma unroll
  for (int h = 0; h < 12; ++h) {
    const float4* k4 = reinterpret_cast<const float4*>(krow + h * 32);
    float nd = 0.f;
    #pragma unroll
    for (int d4 = 0; d4 < 8; ++d4) {
      float4 kv = k4[d4];
      nd += qs[h*32+d4*4]*kv.x + qs[h*32+d4*4+1]*kv.y + qs[h*32+d4*4+2]*kv.z + qs[h*32+d4*4+3]*kv.w;
    }
    const float4* kp4 = reinterpret_cast<const float4*>(kprow + h * 24);
    float sp = 0.f;
    #pragma unroll
    for (int d4 = 0; d4 < 6; ++d4) {
      float4 kv = kp4[d4];
      sp += qps[h*24+d4*4]*kv.x + qps[h*24+d4*4+1]*kv.y + qps[h*24+d4*4+2]*kv.z + qps[h*24+d4*4+3]*kv.w;
    }
    float ssd = q2s[h] + k2row[h] - 2.f * sp;
    lg[h] = (nd * INV_SQRT_QK + lg[h] + ssd * coef[h]) * S3;
  }
  // --- softmax over j (= over threads), per h ---
  #pragma unroll
  for (int h = 0; h < 12; ++h) {
    float v = lg[h];
    #pragma unroll
    for (int s = 32; s > 0; s >>= 1) v = fmaxf(v, __shfl_xor(v, s));
    if (lane == 0) redbuf[wv * 12 + h] = v;
  }
  __syncthreads();
  float M[12];
  #pragma unroll
  for (int h = 0; h < 12; ++h) {
    float m = redbuf[h];
    #pragma unroll
    for (int w = 1; w < 8; ++w) m = fmaxf(m, redbuf[w * 12 + h]);
    M[h] = m;
  }
  __syncthreads();
  #pragma unroll
  for (int h = 0; h < 12; ++h) {
    float e = __expf(lg[h] - M[h]);
    lg[h] = e;
    #pragma unroll
    for (int s = 32; s > 0; s >>= 1) e += __shfl_xor(e, s);
    if (lane == 0) redbuf[wv * 12 + h] = e;
  }
  __syncthreads();
  #pragma unroll
  for (int h = 0; h < 12; ++h) {
    float ssum = redbuf[h];
    #pragma unroll
    for (int w = 1; w < 8; ++w) ssum += redbuf[w * 12 + h];
    alphab[((size_t)i * 12 + h) * 512 + j] = lg[h] / ssum;
  }
}

// ---------------- K3a: feat_p2n = alpha[i] (12x512) @ z[i] (512x64) ----------------
// block = one i, 256 threads (192 compute: h = t>>4, c4 = t&15)
__global__ __launch_bounds__(256) void k3a_p2n(
    const float* __restrict__ alphab, const float* __restrict__ z,
    float* __restrict__ featb) {
  int i = blockIdx.x, tid = threadIdx.x;
  __shared__ float al[12 * 516];   // pad 516
  __shared__ float zt[64 * 68];    // pad 68
  const float4* asrc = reinterpret_cast<const float4*>(alphab + (size_t)i * 6144);
  for (int g = tid; g < 1536; g += 256) {
    int row = g >> 7, c4 = g & 127;
    *reinterpret_cast<float4*>(&al[row * 516 + c4 * 4]) = asrc[row * 128 + c4];
  }
  int h = tid >> 4, c4 = tid & 15;
  float4 acc = {0.f, 0.f, 0.f, 0.f};
  const float4* zsrc = reinterpret_cast<const float4*>(z + (size_t)i * 512 * 64);
  for (int t8 = 0; t8 < 8; ++t8) {
    __syncthreads();  // covers al staging (t8=0) and zt reuse (t8>0)
    for (int g = tid; g < 1024; g += 256) {
      int row = g >> 4, cc = g & 15;
      *reinterpret_cast<float4*>(&zt[row * 68 + cc * 4]) = zsrc[(t8 * 64 + row) * 16 + cc];
    }
    __syncthreads();
    if (tid < 192) {
      const float* ar = al + h * 516 + t8 * 64;
      #pragma unroll
      for (int k4 = 0; k4 < 16; ++k4) {
        float4 a4 = *reinterpret_cast<const float4*>(&ar[k4 * 4]);
        float4 z0 = *reinterpret_cast<const float4*>(&zt[(k4*4+0) * 68 + c4 * 4]);
        float4 z1 = *reinterpret_cast<const float4*>(&zt[(k4*4+1) * 68 + c4 * 4]);
        float4 z2 = *reinterpret_cast<const float4*>(&zt[(k4*4+2) * 68 + c4 * 4]);
        float4 z3 = *reinterpret_cast<const float4*>(&zt[(k4*4+3) * 68 + c4 * 4]);
        FMA4(acc, a4.x, z0); FMA4(acc, a4.y, z1); FMA4(acc, a4.z, z2); FMA4(acc, a4.w, z3);
      }
    }
  }
  if (tid < 192)
    *reinterpret_cast<float4*>(&featb[(size_t)i * 1440 + h * 64 + c4 * 4]) = acc;
}

// ---------------- K3b: feat_node + feat_spatial as tiled GEMM per (h, i-tile-32) ----------------
// grid 192 = h*16 + it; 256 threads (224 compute: 16 row-groups x 14 col-groups of 4)
__global__ __launch_bounds__(256) void k3b_nodevp(
    const float* __restrict__ alphab, const float* __restrict__ proj,
    const float* __restrict__ Rg, const float* __restrict__ tg,
    float* __restrict__ featb) {
  int b = blockIdx.x;
  int h = b >> 4, it = b & 15, i0 = it * 32;
  int tid = threadIdx.x;
  __shared__ float At[32 * 68];   // alpha tile, pad 68
  __shared__ float Bt[64 * 60];   // [v(32)|vp(24)] tile, pad 60
  __shared__ float ag[32 * 24];   // raw vp aggregate (global frame)
  int cg = tid % 14, rg = tid / 14;   // rg 0..17, valid compute rg<16
  int c0 = cg * 4, r0 = rg * 2;
  float4 acc0 = {0,0,0,0}, acc1 = {0,0,0,0};
  for (int t8 = 0; t8 < 8; ++t8) {
    int j0 = t8 * 64;
    __syncthreads();
    // stage At: 32 rows x 16 float4
    for (int g = tid; g < 512; g += 256) {
      int row = g >> 4, cc = g & 15;
      *reinterpret_cast<float4*>(&At[row * 68 + cc * 4]) =
        *reinterpret_cast<const float4*>(&alphab[(((size_t)(i0 + row)) * 12 + h) * 512 + j0 + cc * 4]);
    }
    // stage Bt: 64 rows x 14 float4 (8 v + 6 vp)
    for (int g = tid; g < 896; g += 256) {
      int row = g / 14, u = g % 14;
      const float* pr = proj + (size_t)(j0 + row) * PCOLS;
      float4 vv = (u < 8) ? *reinterpret_cast<const float4*>(&pr[1344 + h * 32 + u * 4])
                          : *reinterpret_cast<const float4*>(&pr[1728 + h * 24 + (u - 8) * 4]);
      int dst = (u < 8) ? u * 4 : 32 + (u - 8) * 4;
      *reinterpret_cast<float4*>(&Bt[row * 60 + dst]) = vv;
    }
    __syncthreads();
    if (rg < 16) {
      #pragma unroll 4
      for (int kk = 0; kk < 64; kk += 4) {
        float4 a0 = *reinterpret_cast<const float4*>(&At[(r0+0) * 68 + kk]);
        float4 a1 = *reinterpret_cast<const float4*>(&At[(r0+1) * 68 + kk]);
        float4 b0 = *reinterpret_cast<const float4*>(&Bt[(kk+0) * 60 + c0]);
        float4 b1 = *reinterpret_cast<const float4*>(&Bt[(kk+1) * 60 + c0]);
        float4 b2 = *reinterpret_cast<const float4*>(&Bt[(kk+2) * 60 + c0]);
        float4 b3 = *reinterpret_cast<const float4*>(&Bt[(kk+3) * 60 + c0]);
        FMA4(acc0, a0.x, b0); FMA4(acc0, a0.y, b1); FMA4(acc0, a0.z, b2); FMA4(acc0, a0.w, b3);
        FMA4(acc1, a1.x, b0); FMA4(acc1, a1.y, b1); FMA4(acc1, a1.z, b2); FMA4(acc1, a1.w, b3);
      }
    }
  }
  __syncthreads();
  if (rg < 16) {
    #pragma unroll
    for (int r = 0; r < 2; ++r) {
      float4 v = (r == 0) ? acc0 : acc1;
      int row = r0 + r;
      if (c0 < 32) {
        *reinterpret_cast<float4*>(&featb[(size_t)(i0 + row) * 1440 + 768 + h * 32 + c0]) = v;
      } else {
        int cc = c0 - 32;
        ag[row * 24 + cc + 0] = v.x; ag[row * 24 + cc + 1] = v.y;
        ag[row * 24 + cc + 2] = v.z; ag[row * 24 + cc + 3] = v.w;
      }
    }
  }
  __syncthreads();
  // g2l epilogue: 32 rows x 8 points, 1 per thread
  {
    int pt = tid;           // 0..255
    int row = pt >> 3, p = pt & 7;
    const float* R  = Rg + (size_t)(i0 + row) * 9;
    const float* tt = tg + (size_t)(i0 + row) * 3;
    float d0 = ag[row * 24 + p * 3 + 0] - tt[0];
    float d1 = ag[row * 24 + p * 3 + 1] - tt[1];
    float d2 = ag[row * 24 + p * 3 + 2] - tt[2];
    float* o = featb + (size_t)(i0 + row) * 1440 + 1152 + h * 24 + p * 3;
    o[0] = R[0]*d0 + R[3]*d1 + R[6]*d2;
    o[1] = R[1]*d0 + R[4]*d1 + R[7]*d2;
    o[2] = R[2]*d0 + R[5]*d1 + R[8]*d2;
  }
}

// ---------------- K4: Wo + residual/LN1 + MLP + residual/LN2 ----------------
__global__ __launch_bounds__(512) void k4_mlp(
    const float* __restrict__ featb, const float* __restrict__ x,
    const float* __restrict__ Wo, const float* __restrict__ bo,
    const float* __restrict__ ln1s, const float* __restrict__ ln1o,
    const float* __restrict__ W1, const float* __restrict__ b1,
    const float* __restrict__ W2, const float* __restrict__ b2,
    const float* __restrict__ W3, const float* __restrict__ b3,
    const float* __restrict__ ln2s, const float* __restrict__ ln2o,
    float* __restrict__ out) {
  int i = blockIdx.x;
  int tid = threadIdx.x;
  int q = tid >> 7, col = tid & 127;
  __shared__ float fs[1440];
  __shared__ float part[4][128];
  __shared__ float stg[128];
  for (int o = tid; o < 1440; o += 512) fs[o] = featb[i * 1440 + o];
  __syncthreads();
  float acc = 0.f;
  {
    const float* Wop = Wo + (size_t)(q * 360) * 128 + col;
    const float* fsp = fs + q * 360;
    #pragma unroll 4
    for (int c = 0; c < 360; ++c) acc += fsp[c] * Wop[(size_t)c * 128];
  }
  part[q][col] = acc;
  __syncthreads();
  float y = part[0][col] + part[1][col] + part[2][col] + part[3][col] + bo[col] + x[i * 128 + col];
  if (q == 0) stg[col] = y;
  __syncthreads();
  float s1 = 0.f, s2 = 0.f;
  for (int c = 0; c < 128; ++c) { float v = stg[c]; s1 += v; s2 += v * v; }
  float mu = s1 * (1.f / 128.f);
  float var = s2 * (1.f / 128.f) - mu * mu;
  float x1 = (y - mu) * rsqrtf(var + 1e-5f) * ln1s[col] + ln1o[col];
  __syncthreads();
  if (q == 0) stg[col] = x1;
  __syncthreads();
  float a = 0.f;
  { const float* Wp = W1 + (q * 32) * 128 + col;
    #pragma unroll
    for (int c = 0; c < 32; ++c) a += stg[q * 32 + c] * Wp[c * 128]; }
  part[q][col] = a;
  __syncthreads();
  float h1 = fmaxf(part[0][col] + part[1][col] + part[2][col] + part[3][col] + b1[col], 0.f);
  __syncthreads();
  if (q == 0) stg[col] = h1;
  __syncthreads();
  a = 0.f;
  { const float* Wp = W2 + (q * 32) * 128 + col;
    #pragma unroll
    for (int c = 0; c < 32; ++c) a += stg[q * 32 + c] * Wp[c * 128]; }
  part[q][col] = a;
  __syncthreads();
  float h2 = fmaxf(part[0][col] + part[1][col] + part[2][col] + part[3][col] + b2[col], 0.f);
  __syncthreads();
  if (q == 0) stg[col] = h2;
  __syncthreads();
  a = 0.f;
  { const float* Wp = W3 + (q * 32) * 128 + col;
    #pragma unroll
    for (int c = 0; c < 32; ++c) a += stg[q * 32 + c] * Wp[c * 128]; }
  part[q][col] = a;
  __syncthreads();
  float y2 = x1 + part[0][col] + part[1][col] + part[2][col] + part[3][col] + b3[col];
  __syncthreads();
  if (q == 0) stg[col] = y2;
  __syncthreads();
  s1 = 0.f; s2 = 0.f;
  for (int c = 0; c < 128; ++c) { float v = stg[c]; s1 += v; s2 += v * v; }
  mu = s1 * (1.f / 128.f);
  var = s2 * (1.f / 128.f) - mu * mu;
  if (q == 0) out[i * 128 + col] = (y2 - mu) * rsqrtf(var + 1e-5f) * ln2s[col] + ln2o[col];
}

// ---------------- launch ----------------
extern "C" void kernel_launch(void* const* d_in, const int* in_sizes, int n_in,
                              void* d_out, int out_size, void* d_ws, size_t ws_size,
                              hipStream_t stream) {
  const float* Rg   = (const float*)d_in[0];
  const float* tg   = (const float*)d_in[1];
  const float* x    = (const float*)d_in[2];
  const float* z    = (const float*)d_in[3];
  // d_in[4] = mask (all true) -> no-op
  const float* Wq   = (const float*)d_in[5];
  const float* Wk   = (const float*)d_in[6];
  const float* Wpair= (const float*)d_in[7];
  const float* Wqp  = (const float*)d_in[8];
  const float* Wkp  = (const float*)d_in[9];
  const float* Wv   = (const float*)d_in[10];
  const float* Wvp  = (const float*)d_in[11];
  const float* sc   = (const float*)d_in[12];
  const float* Wo   = (const float*)d_in[13];
  const float* bo   = (const float*)d_in[14];
  const float* ln1s = (const float*)d_in[15];
  const float* ln1o = (const float*)d_in[16];
  const float* W1   = (const float*)d_in[17];
  const float* b1   = (const float*)d_in[18];
  const float* W2   = (const float*)d_in[19];
  const float* b2   = (const float*)d_in[20];
  const float* W3   = (const float*)d_in[21];
  const float* b3   = (const float*)d_in[22];
  const float* ln2s = (const float*)d_in[23];
  const float* ln2o = (const float*)d_in[24];

  float* ws = (float*)d_ws;
  float* proj   = ws;                        // 512*2016 = 1,032,192
  float* q2b    = proj + 512 * 2016;         // 6144
  float* k2b    = q2b + 6144;                // 6144
  float* alphab = k2b + 6144;                // 512*12*512 = 3,145,728
  float* featb  = alphab + 3145728;          // 512*1440 = 737,280
  // total ~19.7 MB

  k1_gemm  <<<168, 256, 0, stream>>>(x, Wq, Wk, Wqp, Wkp, Wv, Wvp, proj);
  k1b_xform<<<512, 320, 0, stream>>>(Rg, tg, proj, q2b, k2b);
  k2_logits<<<512, 512, 0, stream>>>(proj, q2b, k2b, z, Wpair, sc, alphab);
  k3a_p2n  <<<512, 256, 0, stream>>>(alphab, z, featb);
  k3b_nodevp<<<192, 256, 0, stream>>>(alphab, proj, Rg, tg, featb);
  k4_mlp   <<<512, 512, 0, stream>>>(featb, x, Wo, bo, ln1s, ln1o,
                                     W1, b1, W2, b2, W3, b3, ln2s, ln2o, (float*)d_out);
}

// Round 4
// 161.029 us; speedup vs baseline: 5.4177x; 4.7925x over previous
//
#include <hip/hip_runtime.h>

// N=1, L=512, F=128, C=64, H=12, QK=32, Vd=32, Pq=8, Pv=8
// proj layout per row (2016 cols): [q 0..383][k 384..767][qp 768..1055][kp 1056..1343][v 1344..1727][vp 1728..2015]
#define PCOLS 2016

constexpr float INV_SQRT_QK = 0.17677669529663687f;  // 1/sqrt(32)
constexpr float S3          = 0.57735026918962576f;  // sqrt(1/3)

#define FMA4(acc, s, b) { acc.x += (s)*(b).x; acc.y += (s)*(b).y; acc.z += (s)*(b).z; acc.w += (s)*(b).w; }

// ---------------- K1: all projections as one tiled GEMM ----------------
__global__ __launch_bounds__(256) void k1_gemm(
    const float* __restrict__ x,
    const float* __restrict__ Wq, const float* __restrict__ Wk,
    const float* __restrict__ Wqp, const float* __restrict__ Wkp,
    const float* __restrict__ Wv, const float* __restrict__ Wvp,
    float* __restrict__ proj) {
  int bt = blockIdx.x;            // 0..167
  int it = bt / 21, ot = bt % 21;
  int i0 = it * 64;
  int tid = threadIdx.x;
  int tr = tid >> 5, tc = tid & 31;
  __shared__ float xs[64 * 128];
  for (int idx = tid; idx < 8192; idx += 256) xs[idx] = x[i0 * 128 + idx];
  const float* Wsec; int lofs, width;
  if (ot < 4)       { Wsec = Wq;  lofs = ot * 96;        width = 384; }
  else if (ot < 8)  { Wsec = Wk;  lofs = (ot - 4) * 96;  width = 384; }
  else if (ot < 11) { Wsec = Wqp; lofs = (ot - 8) * 96;  width = 288; }
  else if (ot < 14) { Wsec = Wkp; lofs = (ot - 11) * 96; width = 288; }
  else if (ot < 18) { Wsec = Wv;  lofs = (ot - 14) * 96; width = 384; }
  else              { Wsec = Wvp; lofs = (ot - 18) * 96; width = 288; }
  __syncthreads();
  float acc[8][3];
  #pragma unroll
  for (int r = 0; r < 8; ++r) { acc[r][0] = 0.f; acc[r][1] = 0.f; acc[r][2] = 0.f; }
  const float* wp0 = Wsec + lofs + tc * 3;
  #pragma unroll 4
  for (int f = 0; f < 128; ++f) {
    float w0 = wp0[f * width], w1 = wp0[f * width + 1], w2 = wp0[f * width + 2];
    const float* xr = xs + (tr * 8) * 128 + f;
    #pragma unroll
    for (int r = 0; r < 8; ++r) {
      float xv = xr[r * 128];
      acc[r][0] += xv * w0; acc[r][1] += xv * w1; acc[r][2] += xv * w2;
    }
  }
  int gc = ot * 96 + tc * 3;
  #pragma unroll
  for (int r = 0; r < 8; ++r) {
    float* dst = proj + (size_t)(i0 + tr * 8 + r) * PCOLS + gc;
    dst[0] = acc[r][0]; dst[1] = acc[r][1]; dst[2] = acc[r][2];
  }
}

// ---------------- K1b: l2g transform + compact logit operands Ac/Bc/a2/b2 ----------------
// Ac[h][i][56] = [q_h*(S3/sqrtQK) | qp_h*(-2*S3*cf_h)]; Bc[h][j][56] = [k_h | kp_h]
// a2[h][i] = S3*cf_h*|qp|^2 ; b2[h][j] = S3*cf_h*|kp|^2 ; cf_h = -softplus(sc_h)/12
__global__ __launch_bounds__(256) void k1b_prep(
    const float* __restrict__ Rg, const float* __restrict__ tg, const float* __restrict__ sc,
    float* __restrict__ proj, float* __restrict__ Ac, float* __restrict__ Bc,
    float* __restrict__ a2, float* __restrict__ b2) {
  int j = blockIdx.x, tid = threadIdx.x;
  __shared__ float qk[1344];   // [q 0..383][k 384..767][qp 768..1055][kp 1056..1343]
  __shared__ float vps[288], Rs[9], ts[3], cf[12];
  float* pr = proj + (size_t)j * PCOLS;
  const float4* pr4 = (const float4*)pr;
  for (int g = tid; g < 336; g += 256) ((float4*)qk)[g] = pr4[g];
  for (int g = tid; g < 72; g += 256) ((float4*)vps)[g] = pr4[432 + g];
  if (tid < 9) Rs[tid] = Rg[j * 9 + tid];
  else if (tid < 12) ts[tid - 9] = tg[j * 3 + tid - 9];
  else if (tid < 24) cf[tid - 12] = -log1pf(__expf(sc[tid - 12])) * (1.0f / 12.0f);
  __syncthreads();
  for (int p = tid; p < 288; p += 256) {
    int sec = p / 96, m = p % 96;
    float* P = (sec == 0) ? qk + 768 : (sec == 1) ? qk + 1056 : vps;
    float* pp = P + m * 3;
    float p0 = pp[0], p1 = pp[1], p2 = pp[2];
    pp[0] = Rs[0]*p0 + Rs[1]*p1 + Rs[2]*p2 + ts[0];
    pp[1] = Rs[3]*p0 + Rs[4]*p1 + Rs[5]*p2 + ts[1];
    pp[2] = Rs[6]*p0 + Rs[7]*p1 + Rs[8]*p2 + ts[2];
  }
  __syncthreads();
  for (int g = tid; g < 72; g += 256) ((float4*)pr)[432 + g] = ((float4*)vps)[g];  // vp back
  if (tid < 24) {
    int h = tid % 12;
    const float* s = (tid < 12) ? qk + 768 + h * 24 : qk + 1056 + h * 24;
    float a = 0.f;
    #pragma unroll
    for (int d = 0; d < 24; ++d) a += s[d] * s[d];
    float val = S3 * cf[h] * a;
    if (tid < 12) a2[h * 512 + j] = val; else b2[h * 512 + j] = val;
  }
  float s1 = S3 * INV_SQRT_QK;
  for (int o = tid; o < 672; o += 256) {
    int h = o / 56, d = o % 56;
    float s2 = -2.0f * S3 * cf[h];
    float aval = (d < 32) ? qk[h * 32 + d] * s1 : qk[768 + h * 24 + (d - 32)] * s2;
    float bval = (d < 32) ? qk[384 + h * 32 + d] : qk[1056 + h * 24 + (d - 32)];
    Ac[((size_t)h * 512 + j) * 56 + d] = aval;
    Bc[((size_t)h * 512 + j) * 56 + d] = bval;
  }
}

// ---------------- K2a: pair logits = S3 * z @ Wpair -> alphab[h][i][j] ----------------
__global__ __launch_bounds__(256) void k2a_pair(
    const float* __restrict__ z, const float* __restrict__ Wpair,
    float* __restrict__ alphab) {
  int blk = blockIdx.x;           // 1024 = i*2 + half
  int i = blk >> 1, j0 = (blk & 1) * 256;
  int tid = threadIdx.x;
  __shared__ float zt[256 * 68];  // pad 68 (float4-aligned)
  __shared__ float wp[768];
  for (int g = tid; g < 192; g += 256) ((float4*)wp)[g] = ((const float4*)Wpair)[g];
  const float4* zsrc = (const float4*)(z + ((size_t)i * 512 + j0) * 64);
  for (int g = tid; g < 4096; g += 256) {
    int row = g >> 4, c4 = g & 15;
    ((float4*)(zt + row * 68))[c4] = zsrc[row * 16 + c4];
  }
  __syncthreads();
  float acc[12];
  #pragma unroll
  for (int h = 0; h < 12; ++h) acc[h] = 0.f;
  const float4* zr = (const float4*)(zt + tid * 68);
  #pragma unroll 4
  for (int c4 = 0; c4 < 16; ++c4) {
    float4 zv = zr[c4];
    const float* w0 = wp + c4 * 48;
    #pragma unroll
    for (int h = 0; h < 12; ++h)
      acc[h] += zv.x * w0[h] + zv.y * w0[12 + h] + zv.z * w0[24 + h] + zv.w * w0[36 + h];
  }
  #pragma unroll
  for (int h = 0; h < 12; ++h)
    alphab[(size_t)h * 262144 + (size_t)i * 512 + j0 + tid] = acc[h] * S3;
}

// ---------------- K2b: logits GEMM (K=56) + rank-1 terms + in-register softmax ----------------
// grid 384 = h*32 + it(16 rows); 256 thr = 8 ti x 32 tj; full j row (512) in registers
__global__ __launch_bounds__(256) void k2b_logits(
    const float* __restrict__ Ac, const float* __restrict__ Bc,
    const float* __restrict__ a2, const float* __restrict__ b2,
    float* __restrict__ alphab) {
  int blk = blockIdx.x;
  int h = blk >> 5, i0 = (blk & 31) * 16;
  int tid = threadIdx.x;
  int ti = tid >> 5, tj = tid & 31;
  int r0 = 2 * ti;
  __shared__ float At[16 * 60];
  __shared__ float BtT[56 * 132];
  __shared__ float b2s[512];
  __shared__ float a2s[16];
  for (int g = tid; g < 224; g += 256) {
    int row = g / 14, u = g % 14;
    *(float4*)(At + row * 60 + u * 4) =
      *(const float4*)(Ac + ((size_t)h * 512 + i0 + row) * 56 + u * 4);
  }
  if (tid < 128) ((float4*)b2s)[tid] = ((const float4*)(b2 + h * 512))[tid];
  if (tid < 16) a2s[tid] = a2[h * 512 + i0 + tid];
  float lg[2][16];
  const size_t abase = (size_t)h * 262144;
  for (int jt = 0; jt < 4; ++jt) {
    int j0 = jt * 128;
    __syncthreads();
    for (int g = tid; g < 1792; g += 256) {   // stage B transposed [k][j], pad 132
      int jl = g / 14, u = g % 14;
      float4 v = *(const float4*)(Bc + ((size_t)h * 512 + j0 + jl) * 56 + u * 4);
      BtT[(u * 4 + 0) * 132 + jl] = v.x;
      BtT[(u * 4 + 1) * 132 + jl] = v.y;
      BtT[(u * 4 + 2) * 132 + jl] = v.z;
      BtT[(u * 4 + 3) * 132 + jl] = v.w;
    }
    __syncthreads();
    float acc[2][4] = {{0.f,0.f,0.f,0.f},{0.f,0.f,0.f,0.f}};
    #pragma unroll 8
    for (int k = 0; k < 56; ++k) {
      float a0 = At[r0 * 60 + k], a1 = At[(r0 + 1) * 60 + k];
      float2 bA = *(const float2*)(BtT + k * 132 + 2 * tj);
      float2 bB = *(const float2*)(BtT + k * 132 + 64 + 2 * tj);
      acc[0][0] += a0 * bA.x; acc[0][1] += a0 * bA.y; acc[0][2] += a0 * bB.x; acc[0][3] += a0 * bB.y;
      acc[1][0] += a1 * bA.x; acc[1][1] += a1 * bA.y; acc[1][2] += a1 * bB.x; acc[1][3] += a1 * bB.y;
    }
    #pragma unroll
    for (int r = 0; r < 2; ++r) {
      int ig = i0 + r0 + r;
      const float* prow = alphab + abase + (size_t)ig * 512 + j0;
      int c0 = 2 * tj, c1 = 64 + 2 * tj;
      float arr = a2s[r0 + r];
      lg[r][jt*4+0] = acc[r][0] + prow[c0]     + arr + b2s[j0 + c0];
      lg[r][jt*4+1] = acc[r][1] + prow[c0 + 1] + arr + b2s[j0 + c0 + 1];
      lg[r][jt*4+2] = acc[r][2] + prow[c1]     + arr + b2s[j0 + c1];
      lg[r][jt*4+3] = acc[r][3] + prow[c1 + 1] + arr + b2s[j0 + c1 + 1];
    }
  }
  // exact softmax over j per row: 16 locals + shfl over the 32-lane tj group
  #pragma unroll
  for (int r = 0; r < 2; ++r) {
    float m = lg[r][0];
    #pragma unroll
    for (int u = 1; u < 16; ++u) m = fmaxf(m, lg[r][u]);
    #pragma unroll
    for (int s = 16; s > 0; s >>= 1) m = fmaxf(m, __shfl_xor(m, s));
    float ssum = 0.f;
    #pragma unroll
    for (int u = 0; u < 16; ++u) { lg[r][u] = __expf(lg[r][u] - m); ssum += lg[r][u]; }
    #pragma unroll
    for (int s = 16; s > 0; s >>= 1) ssum += __shfl_xor(ssum, s);
    float inv = 1.0f / ssum;
    float* orow = alphab + abase + (size_t)(i0 + r0 + r) * 512;
    #pragma unroll
    for (int jt = 0; jt < 4; ++jt) {
      *(float2*)(orow + jt * 128 + 2 * tj)      = make_float2(lg[r][jt*4+0] * inv, lg[r][jt*4+1] * inv);
      *(float2*)(orow + jt * 128 + 64 + 2 * tj) = make_float2(lg[r][jt*4+2] * inv, lg[r][jt*4+3] * inv);
    }
  }
}

// ---------------- K3a: feat_p2n = alpha[h][i][:] @ z[i] (512x64) ----------------
__global__ __launch_bounds__(256) void k3a_p2n(
    const float* __restrict__ alphab, const float* __restrict__ z,
    float* __restrict__ featb) {
  int i = blockIdx.x, tid = threadIdx.x;
  __shared__ float al[12 * 516];
  __shared__ float zt[64 * 68];
  for (int g = tid; g < 1536; g += 256) {
    int row = g >> 7, c4 = g & 127;
    *(float4*)(al + row * 516 + c4 * 4) =
      *(const float4*)(alphab + (size_t)row * 262144 + (size_t)i * 512 + c4 * 4);
  }
  int h = tid >> 4, c4 = tid & 15;
  float4 acc = {0.f, 0.f, 0.f, 0.f};
  const float4* zsrc = (const float4*)(z + (size_t)i * 512 * 64);
  for (int t8 = 0; t8 < 8; ++t8) {
    __syncthreads();
    for (int g = tid; g < 1024; g += 256) {
      int row = g >> 4, cc = g & 15;
      *(float4*)(&zt[row * 68 + cc * 4]) = zsrc[(t8 * 64 + row) * 16 + cc];
    }
    __syncthreads();
    if (tid < 192) {
      const float* ar = al + h * 516 + t8 * 64;
      #pragma unroll
      for (int k4 = 0; k4 < 16; ++k4) {
        float4 a4 = *(const float4*)(&ar[k4 * 4]);
        float4 z0 = *(const float4*)(&zt[(k4*4+0) * 68 + c4 * 4]);
        float4 z1 = *(const float4*)(&zt[(k4*4+1) * 68 + c4 * 4]);
        float4 z2 = *(const float4*)(&zt[(k4*4+2) * 68 + c4 * 4]);
        float4 z3 = *(const float4*)(&zt[(k4*4+3) * 68 + c4 * 4]);
        FMA4(acc, a4.x, z0); FMA4(acc, a4.y, z1); FMA4(acc, a4.z, z2); FMA4(acc, a4.w, z3);
      }
    }
  }
  if (tid < 192)
    *(float4*)(&featb[(size_t)i * 1440 + h * 64 + c4 * 4]) = acc;
}

// ---------------- K3b: feat_node + feat_spatial tiled GEMM per (h, i-tile-32) ----------------
__global__ __launch_bounds__(256) void k3b_nodevp(
    const float* __restrict__ alphab, const float* __restrict__ proj,
    const float* __restrict__ Rg, const float* __restrict__ tg,
    float* __restrict__ featb) {
  int b = blockIdx.x;
  int h = b >> 4, it = b & 15, i0 = it * 32;
  int tid = threadIdx.x;
  __shared__ float At[32 * 68];
  __shared__ float Bt[64 * 60];
  __shared__ float ag[32 * 24];
  int cg = tid % 14, rg = tid / 14;
  int c0 = cg * 4, r0 = rg * 2;
  float4 acc0 = {0,0,0,0}, acc1 = {0,0,0,0};
  for (int t8 = 0; t8 < 8; ++t8) {
    int j0 = t8 * 64;
    __syncthreads();
    for (int g = tid; g < 512; g += 256) {
      int row = g >> 4, cc = g & 15;
      *(float4*)(&At[row * 68 + cc * 4]) =
        *(const float4*)(alphab + (size_t)h * 262144 + (size_t)(i0 + row) * 512 + j0 + cc * 4);
    }
    for (int g = tid; g < 896; g += 256) {
      int row = g / 14, u = g % 14;
      const float* pr = proj + (size_t)(j0 + row) * PCOLS;
      float4 vv = (u < 8) ? *(const float4*)(&pr[1344 + h * 32 + u * 4])
                          : *(const float4*)(&pr[1728 + h * 24 + (u - 8) * 4]);
      int dst = (u < 8) ? u * 4 : 32 + (u - 8) * 4;
      *(float4*)(&Bt[row * 60 + dst]) = vv;
    }
    __syncthreads();
    if (rg < 16) {
      #pragma unroll 4
      for (int kk = 0; kk < 64; kk += 4) {
        float4 a0 = *(const float4*)(&At[(r0+0) * 68 + kk]);
        float4 a1 = *(const float4*)(&At[(r0+1) * 68 + kk]);
        float4 b0 = *(const float4*)(&Bt[(kk+0) * 60 + c0]);
        float4 b1 = *(const float4*)(&Bt[(kk+1) * 60 + c0]);
        float4 b2v = *(const float4*)(&Bt[(kk+2) * 60 + c0]);
        float4 b3 = *(const float4*)(&Bt[(kk+3) * 60 + c0]);
        FMA4(acc0, a0.x, b0); FMA4(acc0, a0.y, b1); FMA4(acc0, a0.z, b2v); FMA4(acc0, a0.w, b3);
        FMA4(acc1, a1.x, b0); FMA4(acc1, a1.y, b1); FMA4(acc1, a1.z, b2v); FMA4(acc1, a1.w, b3);
      }
    }
  }
  __syncthreads();
  if (rg < 16) {
    #pragma unroll
    for (int r = 0; r < 2; ++r) {
      float4 v = (r == 0) ? acc0 : acc1;
      int row = r0 + r;
      if (c0 < 32) {
        *(float4*)(&featb[(size_t)(i0 + row) * 1440 + 768 + h * 32 + c0]) = v;
      } else {
        int cc = c0 - 32;
        ag[row * 24 + cc + 0] = v.x; ag[row * 24 + cc + 1] = v.y;
        ag[row * 24 + cc + 2] = v.z; ag[row * 24 + cc + 3] = v.w;
      }
    }
  }
  __syncthreads();
  {
    int row = tid >> 3, p = tid & 7;
    const float* R  = Rg + (size_t)(i0 + row) * 9;
    const float* tt = tg + (size_t)(i0 + row) * 3;
    float d0 = ag[row * 24 + p * 3 + 0] - tt[0];
    float d1 = ag[row * 24 + p * 3 + 1] - tt[1];
    float d2 = ag[row * 24 + p * 3 + 2] - tt[2];
    float* o = featb + (size_t)(i0 + row) * 1440 + 1152 + h * 24 + p * 3;
    o[0] = R[0]*d0 + R[3]*d1 + R[6]*d2;
    o[1] = R[1]*d0 + R[4]*d1 + R[7]*d2;
    o[2] = R[2]*d0 + R[5]*d1 + R[8]*d2;
  }
}

// ---------------- K4: Wo + residual/LN1 + MLP + residual/LN2 ----------------
__global__ __launch_bounds__(512) void k4_mlp(
    const float* __restrict__ featb, const float* __restrict__ x,
    const float* __restrict__ Wo, const float* __restrict__ bo,
    const float* __restrict__ ln1s, const float* __restrict__ ln1o,
    const float* __restrict__ W1, const float* __restrict__ b1,
    const float* __restrict__ W2, const float* __restrict__ b2,
    const float* __restrict__ W3, const float* __restrict__ b3,
    const float* __restrict__ ln2s, const float* __restrict__ ln2o,
    float* __restrict__ out) {
  int i = blockIdx.x;
  int tid = threadIdx.x;
  int q = tid >> 7, col = tid & 127;
  __shared__ float fs[1440];
  __shared__ float part[4][128];
  __shared__ float stg[128];
  for (int o = tid; o < 1440; o += 512) fs[o] = featb[i * 1440 + o];
  __syncthreads();
  float acc = 0.f;
  {
    const float* Wop = Wo + (size_t)(q * 360) * 128 + col;
    const float* fsp = fs + q * 360;
    #pragma unroll 4
    for (int c = 0; c < 360; ++c) acc += fsp[c] * Wop[(size_t)c * 128];
  }
  part[q][col] = acc;
  __syncthreads();
  float y = part[0][col] + part[1][col] + part[2][col] + part[3][col] + bo[col] + x[i * 128 + col];
  if (q == 0) stg[col] = y;
  __syncthreads();
  float s1 = 0.f, s2 = 0.f;
  for (int c = 0; c < 128; ++c) { float v = stg[c]; s1 += v; s2 += v * v; }
  float mu = s1 * (1.f / 128.f);
  float var = s2 * (1.f / 128.f) - mu * mu;
  float x1 = (y - mu) * rsqrtf(var + 1e-5f) * ln1s[col] + ln1o[col];
  __syncthreads();
  if (q == 0) stg[col] = x1;
  __syncthreads();
  float a = 0.f;
  { const float* Wp = W1 + (q * 32) * 128 + col;
    #pragma unroll
    for (int c = 0; c < 32; ++c) a += stg[q * 32 + c] * Wp[c * 128]; }
  part[q][col] = a;
  __syncthreads();
  float h1 = fmaxf(part[0][col] + part[1][col] + part[2][col] + part[3][col] + b1[col], 0.f);
  __syncthreads();
  if (q == 0) stg[col] = h1;
  __syncthreads();
  a = 0.f;
  { const float* Wp = W2 + (q * 32) * 128 + col;
    #pragma unroll
    for (int c = 0; c < 32; ++c) a += stg[q * 32 + c] * Wp[c * 128]; }
  part[q][col] = a;
  __syncthreads();
  float h2 = fmaxf(part[0][col] + part[1][col] + part[2][col] + part[3][col] + b2[col], 0.f);
  __syncthreads();
  if (q == 0) stg[col] = h2;
  __syncthreads();
  a = 0.f;
  { const float* Wp = W3 + (q * 32) * 128 + col;
    #pragma unroll
    for (int c = 0; c < 32; ++c) a += stg[q * 32 + c] * Wp[c * 128]; }
  part[q][col] = a;
  __syncthreads();
  float y2 = x1 + part[0][col] + part[1][col] + part[2][col] + part[3][col] + b3[col];
  __syncthreads();
  if (q == 0) stg[col] = y2;
  __syncthreads();
  s1 = 0.f; s2 = 0.f;
  for (int c = 0; c < 128; ++c) { float v = stg[c]; s1 += v; s2 += v * v; }
  mu = s1 * (1.f / 128.f);
  var = s2 * (1.f / 128.f) - mu * mu;
  if (q == 0) out[i * 128 + col] = (y2 - mu) * rsqrtf(var + 1e-5f) * ln2s[col] + ln2o[col];
}

// ---------------- launch ----------------
extern "C" void kernel_launch(void* const* d_in, const int* in_sizes, int n_in,
                              void* d_out, int out_size, void* d_ws, size_t ws_size,
                              hipStream_t stream) {
  const float* Rg   = (const float*)d_in[0];
  const float* tg   = (const float*)d_in[1];
  const float* x    = (const float*)d_in[2];
  const float* z    = (const float*)d_in[3];
  // d_in[4] = mask (all true) -> no-op
  const float* Wq   = (const float*)d_in[5];
  const float* Wk   = (const float*)d_in[6];
  const float* Wpair= (const float*)d_in[7];
  const float* Wqp  = (const float*)d_in[8];
  const float* Wkp  = (const float*)d_in[9];
  const float* Wv   = (const float*)d_in[10];
  const float* Wvp  = (const float*)d_in[11];
  const float* sc   = (const float*)d_in[12];
  const float* Wo   = (const float*)d_in[13];
  const float* bo   = (const float*)d_in[14];
  const float* ln1s = (const float*)d_in[15];
  const float* ln1o = (const float*)d_in[16];
  const float* W1   = (const float*)d_in[17];
  const float* b1   = (const float*)d_in[18];
  const float* W2   = (const float*)d_in[19];
  const float* b2   = (const float*)d_in[20];
  const float* W3   = (const float*)d_in[21];
  const float* b3   = (const float*)d_in[22];
  const float* ln2s = (const float*)d_in[23];
  const float* ln2o = (const float*)d_in[24];

  float* ws = (float*)d_ws;
  float* proj   = ws;                        // 512*2016 = 1,032,192
  float* Ac     = proj + 512 * 2016;         // 12*512*56 = 344,064
  float* Bc     = Ac + 344064;               // 344,064
  float* a2     = Bc + 344064;               // 6,144
  float* b2v    = a2 + 6144;                 // 6,144
  float* alphab = b2v + 6144;                // 12*512*512 = 3,145,728
  float* featb  = alphab + 3145728;          // 512*1440 = 737,280
  // total ~22.5 MB

  k1_gemm  <<<168, 256, 0, stream>>>(x, Wq, Wk, Wqp, Wkp, Wv, Wvp, proj);
  k1b_prep <<<512, 256, 0, stream>>>(Rg, tg, sc, proj, Ac, Bc, a2, b2v);
  k2a_pair <<<1024, 256, 0, stream>>>(z, Wpair, alphab);
  k2b_logits<<<384, 256, 0, stream>>>(Ac, Bc, a2, b2v, alphab);
  k3a_p2n  <<<512, 256, 0, stream>>>(alphab, z, featb);
  k3b_nodevp<<<192, 256, 0, stream>>>(alphab, proj, Rg, tg, featb);
  k4_mlp   <<<512, 512, 0, stream>>>(featb, x, Wo, bo, ln1s, ln1o,
                                     W1, b1, W2, b2, W3, b3, ln2s, ln2o, (float*)d_out);
}

// Round 5
// 159.646 us; speedup vs baseline: 5.4646x; 1.0087x over previous
//
#include <hip/hip_runtime.h>

// N=1, L=512, F=128, C=64, H=12, QK=32, Vd=32, Pq=8, Pv=8
// proj layout per row (2016 cols): [q 0..383][k 384..767][qp 768..1055][kp 1056..1343][v 1344..1727][vp 1728..2015]
#define PCOLS 2016

constexpr float INV_SQRT_QK = 0.17677669529663687f;  // 1/sqrt(32)
constexpr float S3          = 0.57735026918962576f;  // sqrt(1/3)

#define FMA4(acc, s, b) { acc.x += (s)*(b).x; acc.y += (s)*(b).y; acc.z += (s)*(b).z; acc.w += (s)*(b).w; }

// ---------------- K1: all projections as one tiled GEMM ----------------
__global__ __launch_bounds__(256) void k1_gemm(
    const float* __restrict__ x,
    const float* __restrict__ Wq, const float* __restrict__ Wk,
    const float* __restrict__ Wqp, const float* __restrict__ Wkp,
    const float* __restrict__ Wv, const float* __restrict__ Wvp,
    float* __restrict__ proj) {
  int bt = blockIdx.x;            // 0..167
  int it = bt / 21, ot = bt % 21;
  int i0 = it * 64;
  int tid = threadIdx.x;
  int tr = tid >> 5, tc = tid & 31;
  __shared__ float xs[64 * 128];
  for (int idx = tid; idx < 8192; idx += 256) xs[idx] = x[i0 * 128 + idx];
  const float* Wsec; int lofs, width;
  if (ot < 4)       { Wsec = Wq;  lofs = ot * 96;        width = 384; }
  else if (ot < 8)  { Wsec = Wk;  lofs = (ot - 4) * 96;  width = 384; }
  else if (ot < 11) { Wsec = Wqp; lofs = (ot - 8) * 96;  width = 288; }
  else if (ot < 14) { Wsec = Wkp; lofs = (ot - 11) * 96; width = 288; }
  else if (ot < 18) { Wsec = Wv;  lofs = (ot - 14) * 96; width = 384; }
  else              { Wsec = Wvp; lofs = (ot - 18) * 96; width = 288; }
  __syncthreads();
  float acc[8][3];
  #pragma unroll
  for (int r = 0; r < 8; ++r) { acc[r][0] = 0.f; acc[r][1] = 0.f; acc[r][2] = 0.f; }
  const float* wp0 = Wsec + lofs + tc * 3;
  #pragma unroll 4
  for (int f = 0; f < 128; ++f) {
    float w0 = wp0[f * width], w1 = wp0[f * width + 1], w2 = wp0[f * width + 2];
    const float* xr = xs + (tr * 8) * 128 + f;
    #pragma unroll
    for (int r = 0; r < 8; ++r) {
      float xv = xr[r * 128];
      acc[r][0] += xv * w0; acc[r][1] += xv * w1; acc[r][2] += xv * w2;
    }
  }
  int gc = ot * 96 + tc * 3;
  #pragma unroll
  for (int r = 0; r < 8; ++r) {
    float* dst = proj + (size_t)(i0 + tr * 8 + r) * PCOLS + gc;
    dst[0] = acc[r][0]; dst[1] = acc[r][1]; dst[2] = acc[r][2];
  }
}

// ---------------- K1b: l2g transform + compact logit operands Ac/Bc/a2/b2 ----------------
__global__ __launch_bounds__(256) void k1b_prep(
    const float* __restrict__ Rg, const float* __restrict__ tg, const float* __restrict__ sc,
    float* __restrict__ proj, float* __restrict__ Ac, float* __restrict__ Bc,
    float* __restrict__ a2, float* __restrict__ b2) {
  int j = blockIdx.x, tid = threadIdx.x;
  __shared__ float qk[1344];   // [q][k][qp][kp]
  __shared__ float vps[288], Rs[9], ts[3], cf[12];
  float* pr = proj + (size_t)j * PCOLS;
  const float4* pr4 = (const float4*)pr;
  for (int g = tid; g < 336; g += 256) ((float4*)qk)[g] = pr4[g];
  for (int g = tid; g < 72; g += 256) ((float4*)vps)[g] = pr4[432 + g];
  if (tid < 9) Rs[tid] = Rg[j * 9 + tid];
  else if (tid < 12) ts[tid - 9] = tg[j * 3 + tid - 9];
  else if (tid < 24) cf[tid - 12] = -log1pf(__expf(sc[tid - 12])) * (1.0f / 12.0f);
  __syncthreads();
  for (int p = tid; p < 288; p += 256) {
    int sec = p / 96, m = p % 96;
    float* P = (sec == 0) ? qk + 768 : (sec == 1) ? qk + 1056 : vps;
    float* pp = P + m * 3;
    float p0 = pp[0], p1 = pp[1], p2 = pp[2];
    pp[0] = Rs[0]*p0 + Rs[1]*p1 + Rs[2]*p2 + ts[0];
    pp[1] = Rs[3]*p0 + Rs[4]*p1 + Rs[5]*p2 + ts[1];
    pp[2] = Rs[6]*p0 + Rs[7]*p1 + Rs[8]*p2 + ts[2];
  }
  __syncthreads();
  for (int g = tid; g < 72; g += 256) ((float4*)pr)[432 + g] = ((float4*)vps)[g];  // vp back
  if (tid < 24) {
    int h = tid % 12;
    const float* s = (tid < 12) ? qk + 768 + h * 24 : qk + 1056 + h * 24;
    float a = 0.f;
    #pragma unroll
    for (int d = 0; d < 24; ++d) a += s[d] * s[d];
    float val = S3 * cf[h] * a;
    if (tid < 12) a2[h * 512 + j] = val; else b2[h * 512 + j] = val;
  }
  float s1 = S3 * INV_SQRT_QK;
  for (int o = tid; o < 672; o += 256) {
    int h = o / 56, d = o % 56;
    float s2 = -2.0f * S3 * cf[h];
    float aval = (d < 32) ? qk[h * 32 + d] * s1 : qk[768 + h * 24 + (d - 32)] * s2;
    float bval = (d < 32) ? qk[384 + h * 32 + d] : qk[1056 + h * 24 + (d - 32)];
    Ac[((size_t)h * 512 + j) * 56 + d] = aval;
    Bc[((size_t)h * 512 + j) * 56 + d] = bval;
  }
}

// ---------------- K2a: pair logits = S3 * z @ Wpair -> alphab[h][i][j] ----------------
__global__ __launch_bounds__(256) void k2a_pair(
    const float* __restrict__ z, const float* __restrict__ Wpair,
    float* __restrict__ alphab) {
  int blk = blockIdx.x;           // 1024 = i*2 + half
  int i = blk >> 1, j0 = (blk & 1) * 256;
  int tid = threadIdx.x;
  __shared__ float zt[256 * 68];
  __shared__ float wp[768];
  for (int g = tid; g < 192; g += 256) ((float4*)wp)[g] = ((const float4*)Wpair)[g];
  const float4* zsrc = (const float4*)(z + ((size_t)i * 512 + j0) * 64);
  for (int g = tid; g < 4096; g += 256) {
    int row = g >> 4, c4 = g & 15;
    ((float4*)(zt + row * 68))[c4] = zsrc[row * 16 + c4];
  }
  __syncthreads();
  float acc[12];
  #pragma unroll
  for (int h = 0; h < 12; ++h) acc[h] = 0.f;
  const float4* zr = (const float4*)(zt + tid * 68);
  #pragma unroll 4
  for (int c4 = 0; c4 < 16; ++c4) {
    float4 zv = zr[c4];
    const float* w0 = wp + c4 * 48;
    #pragma unroll
    for (int h = 0; h < 12; ++h)
      acc[h] += zv.x * w0[h] + zv.y * w0[12 + h] + zv.z * w0[24 + h] + zv.w * w0[36 + h];
  }
  #pragma unroll
  for (int h = 0; h < 12; ++h)
    alphab[(size_t)h * 262144 + (size_t)i * 512 + j0 + tid] = acc[h] * S3;
}

// ---------------- K2b: logits GEMM (K=56) + rank-1 terms + in-register softmax ----------------
__global__ __launch_bounds__(256) void k2b_logits(
    const float* __restrict__ Ac, const float* __restrict__ Bc,
    const float* __restrict__ a2, const float* __restrict__ b2,
    float* __restrict__ alphab) {
  int blk = blockIdx.x;
  int h = blk >> 5, i0 = (blk & 31) * 16;
  int tid = threadIdx.x;
  int ti = tid >> 5, tj = tid & 31;
  int r0 = 2 * ti;
  __shared__ float At[16 * 60];
  __shared__ float BtT[56 * 132];
  __shared__ float b2s[512];
  __shared__ float a2s[16];
  for (int g = tid; g < 224; g += 256) {
    int row = g / 14, u = g % 14;
    *(float4*)(At + row * 60 + u * 4) =
      *(const float4*)(Ac + ((size_t)h * 512 + i0 + row) * 56 + u * 4);
  }
  if (tid < 128) ((float4*)b2s)[tid] = ((const float4*)(b2 + h * 512))[tid];
  if (tid < 16) a2s[tid] = a2[h * 512 + i0 + tid];
  float lg[2][16];
  const size_t abase = (size_t)h * 262144;
  for (int jt = 0; jt < 4; ++jt) {
    int j0 = jt * 128;
    __syncthreads();
    for (int g = tid; g < 1792; g += 256) {
      int jl = g / 14, u = g % 14;
      float4 v = *(const float4*)(Bc + ((size_t)h * 512 + j0 + jl) * 56 + u * 4);
      BtT[(u * 4 + 0) * 132 + jl] = v.x;
      BtT[(u * 4 + 1) * 132 + jl] = v.y;
      BtT[(u * 4 + 2) * 132 + jl] = v.z;
      BtT[(u * 4 + 3) * 132 + jl] = v.w;
    }
    __syncthreads();
    float acc[2][4] = {{0.f,0.f,0.f,0.f},{0.f,0.f,0.f,0.f}};
    #pragma unroll 8
    for (int k = 0; k < 56; ++k) {
      float a0 = At[r0 * 60 + k], a1 = At[(r0 + 1) * 60 + k];
      float2 bA = *(const float2*)(BtT + k * 132 + 2 * tj);
      float2 bB = *(const float2*)(BtT + k * 132 + 64 + 2 * tj);
      acc[0][0] += a0 * bA.x; acc[0][1] += a0 * bA.y; acc[0][2] += a0 * bB.x; acc[0][3] += a0 * bB.y;
      acc[1][0] += a1 * bA.x; acc[1][1] += a1 * bA.y; acc[1][2] += a1 * bB.x; acc[1][3] += a1 * bB.y;
    }
    #pragma unroll
    for (int r = 0; r < 2; ++r) {
      int ig = i0 + r0 + r;
      const float* prow = alphab + abase + (size_t)ig * 512 + j0;
      int c0 = 2 * tj, c1 = 64 + 2 * tj;
      float arr = a2s[r0 + r];
      lg[r][jt*4+0] = acc[r][0] + prow[c0]     + arr + b2s[j0 + c0];
      lg[r][jt*4+1] = acc[r][1] + prow[c0 + 1] + arr + b2s[j0 + c0 + 1];
      lg[r][jt*4+2] = acc[r][2] + prow[c1]     + arr + b2s[j0 + c1];
      lg[r][jt*4+3] = acc[r][3] + prow[c1 + 1] + arr + b2s[j0 + c1 + 1];
    }
  }
  #pragma unroll
  for (int r = 0; r < 2; ++r) {
    float m = lg[r][0];
    #pragma unroll
    for (int u = 1; u < 16; ++u) m = fmaxf(m, lg[r][u]);
    #pragma unroll
    for (int s = 16; s > 0; s >>= 1) m = fmaxf(m, __shfl_xor(m, s));
    float ssum = 0.f;
    #pragma unroll
    for (int u = 0; u < 16; ++u) { lg[r][u] = __expf(lg[r][u] - m); ssum += lg[r][u]; }
    #pragma unroll
    for (int s = 16; s > 0; s >>= 1) ssum += __shfl_xor(ssum, s);
    float inv = 1.0f / ssum;
    float* orow = alphab + abase + (size_t)(i0 + r0 + r) * 512;
    #pragma unroll
    for (int jt = 0; jt < 4; ++jt) {
      *(float2*)(orow + jt * 128 + 2 * tj)      = make_float2(lg[r][jt*4+0] * inv, lg[r][jt*4+1] * inv);
      *(float2*)(orow + jt * 128 + 64 + 2 * tj) = make_float2(lg[r][jt*4+2] * inv, lg[r][jt*4+3] * inv);
    }
  }
}

// ---------------- K3a: feat_p2n = alpha[h][i][:] @ z[i] (512x64) ----------------
__global__ __launch_bounds__(256) void k3a_p2n(
    const float* __restrict__ alphab, const float* __restrict__ z,
    float* __restrict__ featb) {
  int i = blockIdx.x, tid = threadIdx.x;
  __shared__ float al[12 * 516];
  __shared__ float zt[64 * 68];
  for (int g = tid; g < 1536; g += 256) {
    int row = g >> 7, c4 = g & 127;
    *(float4*)(al + row * 516 + c4 * 4) =
      *(const float4*)(alphab + (size_t)row * 262144 + (size_t)i * 512 + c4 * 4);
  }
  int h = tid >> 4, c4 = tid & 15;
  float4 acc = {0.f, 0.f, 0.f, 0.f};
  const float4* zsrc = (const float4*)(z + (size_t)i * 512 * 64);
  for (int t8 = 0; t8 < 8; ++t8) {
    __syncthreads();
    for (int g = tid; g < 1024; g += 256) {
      int row = g >> 4, cc = g & 15;
      *(float4*)(&zt[row * 68 + cc * 4]) = zsrc[(t8 * 64 + row) * 16 + cc];
    }
    __syncthreads();
    if (tid < 192) {
      const float* ar = al + h * 516 + t8 * 64;
      #pragma unroll
      for (int k4 = 0; k4 < 16; ++k4) {
        float4 a4 = *(const float4*)(&ar[k4 * 4]);
        float4 z0 = *(const float4*)(&zt[(k4*4+0) * 68 + c4 * 4]);
        float4 z1 = *(const float4*)(&zt[(k4*4+1) * 68 + c4 * 4]);
        float4 z2 = *(const float4*)(&zt[(k4*4+2) * 68 + c4 * 4]);
        float4 z3 = *(const float4*)(&zt[(k4*4+3) * 68 + c4 * 4]);
        FMA4(acc, a4.x, z0); FMA4(acc, a4.y, z1); FMA4(acc, a4.z, z2); FMA4(acc, a4.w, z3);
      }
    }
  }
  if (tid < 192)
    *(float4*)(&featb[(size_t)i * 1440 + h * 64 + c4 * 4]) = acc;
}

// ---------------- K3b: feat_node + feat_spatial tiled GEMM per (h, i-tile-32) ----------------
__global__ __launch_bounds__(256) void k3b_nodevp(
    const float* __restrict__ alphab, const float* __restrict__ proj,
    const float* __restrict__ Rg, const float* __restrict__ tg,
    float* __restrict__ featb) {
  int b = blockIdx.x;
  int h = b >> 4, it = b & 15, i0 = it * 32;
  int tid = threadIdx.x;
  __shared__ float At[32 * 68];
  __shared__ float Bt[64 * 60];
  __shared__ float ag[32 * 24];
  int cg = tid % 14, rg = tid / 14;
  int c0 = cg * 4, r0 = rg * 2;
  float4 acc0 = {0,0,0,0}, acc1 = {0,0,0,0};
  for (int t8 = 0; t8 < 8; ++t8) {
    int j0 = t8 * 64;
    __syncthreads();
    for (int g = tid; g < 512; g += 256) {
      int row = g >> 4, cc = g & 15;
      *(float4*)(&At[row * 68 + cc * 4]) =
        *(const float4*)(alphab + (size_t)h * 262144 + (size_t)(i0 + row) * 512 + j0 + cc * 4);
    }
    for (int g = tid; g < 896; g += 256) {
      int row = g / 14, u = g % 14;
      const float* pr = proj + (size_t)(j0 + row) * PCOLS;
      float4 vv = (u < 8) ? *(const float4*)(&pr[1344 + h * 32 + u * 4])
                          : *(const float4*)(&pr[1728 + h * 24 + (u - 8) * 4]);
      int dst = (u < 8) ? u * 4 : 32 + (u - 8) * 4;
      *(float4*)(&Bt[row * 60 + dst]) = vv;
    }
    __syncthreads();
    if (rg < 16) {
      #pragma unroll 4
      for (int kk = 0; kk < 64; kk += 4) {
        float4 a0 = *(const float4*)(&At[(r0+0) * 68 + kk]);
        float4 a1 = *(const float4*)(&At[(r0+1) * 68 + kk]);
        float4 b0 = *(const float4*)(&Bt[(kk+0) * 60 + c0]);
        float4 b1 = *(const float4*)(&Bt[(kk+1) * 60 + c0]);
        float4 b2v = *(const float4*)(&Bt[(kk+2) * 60 + c0]);
        float4 b3 = *(const float4*)(&Bt[(kk+3) * 60 + c0]);
        FMA4(acc0, a0.x, b0); FMA4(acc0, a0.y, b1); FMA4(acc0, a0.z, b2v); FMA4(acc0, a0.w, b3);
        FMA4(acc1, a1.x, b0); FMA4(acc1, a1.y, b1); FMA4(acc1, a1.z, b2v); FMA4(acc1, a1.w, b3);
      }
    }
  }
  __syncthreads();
  if (rg < 16) {
    #pragma unroll
    for (int r = 0; r < 2; ++r) {
      float4 v = (r == 0) ? acc0 : acc1;
      int row = r0 + r;
      if (c0 < 32) {
        *(float4*)(&featb[(size_t)(i0 + row) * 1440 + 768 + h * 32 + c0]) = v;
      } else {
        int cc = c0 - 32;
        ag[row * 24 + cc + 0] = v.x; ag[row * 24 + cc + 1] = v.y;
        ag[row * 24 + cc + 2] = v.z; ag[row * 24 + cc + 3] = v.w;
      }
    }
  }
  __syncthreads();
  {
    int row = tid >> 3, p = tid & 7;
    const float* R  = Rg + (size_t)(i0 + row) * 9;
    const float* tt = tg + (size_t)(i0 + row) * 3;
    float d0 = ag[row * 24 + p * 3 + 0] - tt[0];
    float d1 = ag[row * 24 + p * 3 + 1] - tt[1];
    float d2 = ag[row * 24 + p * 3 + 2] - tt[2];
    float* o = featb + (size_t)(i0 + row) * 1440 + 1152 + h * 24 + p * 3;
    o[0] = R[0]*d0 + R[3]*d1 + R[6]*d2;
    o[1] = R[1]*d0 + R[4]*d1 + R[7]*d2;
    o[2] = R[2]*d0 + R[5]*d1 + R[8]*d2;
  }
}

// ---------------- K4: Wo GEMM (4 rows/block) + LN1 + MLP + LN2, fully parallel tail ----------------
// 128 blocks x 512 threads; Wo phase: q=tid>>7 k-split, acc over 4 rows.
// Tail: thread = (row rr=q, col) -> all 4 rows' LN/GEMV run concurrently.
__global__ __launch_bounds__(512) void k4_mlp(
    const float* __restrict__ featb, const float* __restrict__ x,
    const float* __restrict__ Wo, const float* __restrict__ bo,
    const float* __restrict__ ln1s, const float* __restrict__ ln1o,
    const float* __restrict__ W1, const float* __restrict__ b1,
    const float* __restrict__ W2, const float* __restrict__ b2,
    const float* __restrict__ W3, const float* __restrict__ b3,
    const float* __restrict__ ln2s, const float* __restrict__ ln2o,
    float* __restrict__ out) {
  constexpr int RW = 4;
  int i0 = blockIdx.x * RW;
  int tid = threadIdx.x;
  int q = tid >> 7, col = tid & 127;
  __shared__ float fs[RW][1440];      // 23 KB
  __shared__ float part[4][RW][128];  // 8 KB
  __shared__ float stg[RW][128];      // 2 KB
  for (int o = tid; o < RW * 1440; o += 512) fs[o / 1440][o % 1440] = featb[(size_t)i0 * 1440 + o];
  __syncthreads();
  // --- Wo GEMM: acc[r] = sum_c fs[r][c] * Wo[c][col], c in q's quarter ---
  float acc[RW] = {0.f, 0.f, 0.f, 0.f};
  {
    const float* Wop = Wo + (size_t)(q * 360) * 128 + col;
    const int cb = q * 360;
    for (int c4 = 0; c4 < 90; ++c4) {
      float4 f0 = *(const float4*)&fs[0][cb + c4 * 4];
      float4 f1 = *(const float4*)&fs[1][cb + c4 * 4];
      float4 f2 = *(const float4*)&fs[2][cb + c4 * 4];
      float4 f3 = *(const float4*)&fs[3][cb + c4 * 4];
      float w0 = Wop[(size_t)(c4 * 4 + 0) * 128];
      float w1 = Wop[(size_t)(c4 * 4 + 1) * 128];
      float w2 = Wop[(size_t)(c4 * 4 + 2) * 128];
      float w3 = Wop[(size_t)(c4 * 4 + 3) * 128];
      acc[0] += f0.x * w0 + f0.y * w1 + f0.z * w2 + f0.w * w3;
      acc[1] += f1.x * w0 + f1.y * w1 + f1.z * w2 + f1.w * w3;
      acc[2] += f2.x * w0 + f2.y * w1 + f2.z * w2 + f2.w * w3;
      acc[3] += f3.x * w0 + f3.y * w1 + f3.z * w2 + f3.w * w3;
    }
  }
  #pragma unroll
  for (int r = 0; r < RW; ++r) part[q][r][col] = acc[r];
  __syncthreads();
  const int rr = q;   // tail: thread handles (row rr, col)
  float y = part[0][rr][col] + part[1][rr][col] + part[2][rr][col] + part[3][rr][col]
          + bo[col] + x[(size_t)(i0 + rr) * 128 + col];
  stg[rr][col] = y;
  __syncthreads();
  float s1 = 0.f, s2 = 0.f;
  #pragma unroll 8
  for (int c4 = 0; c4 < 32; ++c4) {
    float4 v = *(const float4*)&stg[rr][c4 * 4];
    s1 += v.x + v.y + v.z + v.w;
    s2 += v.x * v.x + v.y * v.y + v.z * v.z + v.w * v.w;
  }
  float mu = s1 * (1.f / 128.f);
  float var = s2 * (1.f / 128.f) - mu * mu;
  float x1 = (y - mu) * rsqrtf(var + 1e-5f) * ln1s[col] + ln1o[col];
  __syncthreads();
  stg[rr][col] = x1;
  __syncthreads();
  // --- W1 ---
  float a = b1[col];
  {
    const float* Wp = W1 + col;
    #pragma unroll 8
    for (int c4 = 0; c4 < 32; ++c4) {
      float4 f = *(const float4*)&stg[rr][c4 * 4];
      a += f.x * Wp[(c4 * 4 + 0) * 128] + f.y * Wp[(c4 * 4 + 1) * 128]
         + f.z * Wp[(c4 * 4 + 2) * 128] + f.w * Wp[(c4 * 4 + 3) * 128];
    }
  }
  a = fmaxf(a, 0.f);
  __syncthreads();
  stg[rr][col] = a;
  __syncthreads();
  // --- W2 ---
  a = b2[col];
  {
    const float* Wp = W2 + col;
    #pragma unroll 8
    for (int c4 = 0; c4 < 32; ++c4) {
      float4 f = *(const float4*)&stg[rr][c4 * 4];
      a += f.x * Wp[(c4 * 4 + 0) * 128] + f.y * Wp[(c4 * 4 + 1) * 128]
         + f.z * Wp[(c4 * 4 + 2) * 128] + f.w * Wp[(c4 * 4 + 3) * 128];
    }
  }
  a = fmaxf(a, 0.f);
  __syncthreads();
  stg[rr][col] = a;
  __syncthreads();
  // --- W3 + residual ---
  a = b3[col];
  {
    const float* Wp = W3 + col;
    #pragma unroll 8
    for (int c4 = 0; c4 < 32; ++c4) {
      float4 f = *(const float4*)&stg[rr][c4 * 4];
      a += f.x * Wp[(c4 * 4 + 0) * 128] + f.y * Wp[(c4 * 4 + 1) * 128]
         + f.z * Wp[(c4 * 4 + 2) * 128] + f.w * Wp[(c4 * 4 + 3) * 128];
    }
  }
  float y2 = x1 + a;
  __syncthreads();
  stg[rr][col] = y2;
  __syncthreads();
  s1 = 0.f; s2 = 0.f;
  #pragma unroll 8
  for (int c4 = 0; c4 < 32; ++c4) {
    float4 v = *(const float4*)&stg[rr][c4 * 4];
    s1 += v.x + v.y + v.z + v.w;
    s2 += v.x * v.x + v.y * v.y + v.z * v.z + v.w * v.w;
  }
  mu = s1 * (1.f / 128.f);
  var = s2 * (1.f / 128.f) - mu * mu;
  out[(size_t)(i0 + rr) * 128 + col] = (y2 - mu) * rsqrtf(var + 1e-5f) * ln2s[col] + ln2o[col];
}

// ---------------- launch ----------------
extern "C" void kernel_launch(void* const* d_in, const int* in_sizes, int n_in,
                              void* d_out, int out_size, void* d_ws, size_t ws_size,
                              hipStream_t stream) {
  const float* Rg   = (const float*)d_in[0];
  const float* tg   = (const float*)d_in[1];
  const float* x    = (const float*)d_in[2];
  const float* z    = (const float*)d_in[3];
  // d_in[4] = mask (all true) -> no-op
  const float* Wq   = (const float*)d_in[5];
  const float* Wk   = (const float*)d_in[6];
  const float* Wpair= (const float*)d_in[7];
  const float* Wqp  = (const float*)d_in[8];
  const float* Wkp  = (const float*)d_in[9];
  const float* Wv   = (const float*)d_in[10];
  const float* Wvp  = (const float*)d_in[11];
  const float* sc   = (const float*)d_in[12];
  const float* Wo   = (const float*)d_in[13];
  const float* bo   = (const float*)d_in[14];
  const float* ln1s = (const float*)d_in[15];
  const float* ln1o = (const float*)d_in[16];
  const float* W1   = (const float*)d_in[17];
  const float* b1   = (const float*)d_in[18];
  const float* W2   = (const float*)d_in[19];
  const float* b2   = (const float*)d_in[20];
  const float* W3   = (const float*)d_in[21];
  const float* b3   = (const float*)d_in[22];
  const float* ln2s = (const float*)d_in[23];
  const float* ln2o = (const float*)d_in[24];

  float* ws = (float*)d_ws;
  float* proj   = ws;                        // 512*2016
  float* Ac     = proj + 512 * 2016;         // 12*512*56
  float* Bc     = Ac + 344064;
  float* a2     = Bc + 344064;
  float* b2v    = a2 + 6144;
  float* alphab = b2v + 6144;                // 12*512*512
  float* featb  = alphab + 3145728;          // 512*1440

  k1_gemm  <<<168, 256, 0, stream>>>(x, Wq, Wk, Wqp, Wkp, Wv, Wvp, proj);
  k1b_prep <<<512, 256, 0, stream>>>(Rg, tg, sc, proj, Ac, Bc, a2, b2v);
  k2a_pair <<<1024, 256, 0, stream>>>(z, Wpair, alphab);
  k2b_logits<<<384, 256, 0, stream>>>(Ac, Bc, a2, b2v, alphab);
  k3a_p2n  <<<512, 256, 0, stream>>>(alphab, z, featb);
  k3b_nodevp<<<192, 256, 0, stream>>>(alphab, proj, Rg, tg, featb);
  k4_mlp   <<<128, 512, 0, stream>>>(featb, x, Wo, bo, ln1s, ln1o,
                                     W1, b1, W2, b2, W3, b3, ln2s, ln2o, (float*)d_out);
}

// Round 6
// 141.910 us; speedup vs baseline: 6.1476x; 1.1250x over previous
//
#include <hip/hip_runtime.h>

// N=1, L=512, F=128, C=64, H=12, QK=32, Vd=32, Pq=8, Pv=8
// proj layout per row (2016 cols): [q 0..383][k 384..767][qp 768..1055][kp 1056..1343][v 1344..1727][vp 1728..2015]
#define PCOLS 2016

constexpr float INV_SQRT_QK = 0.17677669529663687f;  // 1/sqrt(32)
constexpr float S3          = 0.57735026918962576f;  // sqrt(1/3)

#define FMA4(acc, s, b) { acc.x += (s)*(b).x; acc.y += (s)*(b).y; acc.z += (s)*(b).z; acc.w += (s)*(b).w; }
#define ADD4(acc, b)    { acc.x += (b).x; acc.y += (b).y; acc.z += (b).z; acc.w += (b).w; }

// ---------------- K1: all projections as one tiled GEMM ----------------
__global__ __launch_bounds__(256) void k1_gemm(
    const float* __restrict__ x,
    const float* __restrict__ Wq, const float* __restrict__ Wk,
    const float* __restrict__ Wqp, const float* __restrict__ Wkp,
    const float* __restrict__ Wv, const float* __restrict__ Wvp,
    float* __restrict__ proj) {
  int bt = blockIdx.x;            // 0..167
  int it = bt / 21, ot = bt % 21;
  int i0 = it * 64;
  int tid = threadIdx.x;
  int tr = tid >> 5, tc = tid & 31;
  __shared__ float xs[64 * 128];
  for (int idx = tid; idx < 8192; idx += 256) xs[idx] = x[i0 * 128 + idx];
  const float* Wsec; int lofs, width;
  if (ot < 4)       { Wsec = Wq;  lofs = ot * 96;        width = 384; }
  else if (ot < 8)  { Wsec = Wk;  lofs = (ot - 4) * 96;  width = 384; }
  else if (ot < 11) { Wsec = Wqp; lofs = (ot - 8) * 96;  width = 288; }
  else if (ot < 14) { Wsec = Wkp; lofs = (ot - 11) * 96; width = 288; }
  else if (ot < 18) { Wsec = Wv;  lofs = (ot - 14) * 96; width = 384; }
  else              { Wsec = Wvp; lofs = (ot - 18) * 96; width = 288; }
  __syncthreads();
  float acc[8][3];
  #pragma unroll
  for (int r = 0; r < 8; ++r) { acc[r][0] = 0.f; acc[r][1] = 0.f; acc[r][2] = 0.f; }
  const float* wp0 = Wsec + lofs + tc * 3;
  #pragma unroll 4
  for (int f = 0; f < 128; ++f) {
    float w0 = wp0[f * width], w1 = wp0[f * width + 1], w2 = wp0[f * width + 2];
    const float* xr = xs + (tr * 8) * 128 + f;
    #pragma unroll
    for (int r = 0; r < 8; ++r) {
      float xv = xr[r * 128];
      acc[r][0] += xv * w0; acc[r][1] += xv * w1; acc[r][2] += xv * w2;
    }
  }
  int gc = ot * 96 + tc * 3;
  #pragma unroll
  for (int r = 0; r < 8; ++r) {
    float* dst = proj + (size_t)(i0 + tr * 8 + r) * PCOLS + gc;
    dst[0] = acc[r][0]; dst[1] = acc[r][1]; dst[2] = acc[r][2];
  }
}

// ---------------- K1b: l2g transform + compact logit operands Ac/Bc/a2/b2 ----------------
__global__ __launch_bounds__(256) void k1b_prep(
    const float* __restrict__ Rg, const float* __restrict__ tg, const float* __restrict__ sc,
    float* __restrict__ proj, float* __restrict__ Ac, float* __restrict__ Bc,
    float* __restrict__ a2, float* __restrict__ b2) {
  int j = blockIdx.x, tid = threadIdx.x;
  __shared__ float qk[1344];   // [q][k][qp][kp]
  __shared__ float vps[288], Rs[9], ts[3], cf[12];
  float* pr = proj + (size_t)j * PCOLS;
  const float4* pr4 = (const float4*)pr;
  for (int g = tid; g < 336; g += 256) ((float4*)qk)[g] = pr4[g];
  for (int g = tid; g < 72; g += 256) ((float4*)vps)[g] = pr4[432 + g];
  if (tid < 9) Rs[tid] = Rg[j * 9 + tid];
  else if (tid < 12) ts[tid - 9] = tg[j * 3 + tid - 9];
  else if (tid < 24) cf[tid - 12] = -log1pf(__expf(sc[tid - 12])) * (1.0f / 12.0f);
  __syncthreads();
  for (int p = tid; p < 288; p += 256) {
    int sec = p / 96, m = p % 96;
    float* P = (sec == 0) ? qk + 768 : (sec == 1) ? qk + 1056 : vps;
    float* pp = P + m * 3;
    float p0 = pp[0], p1 = pp[1], p2 = pp[2];
    pp[0] = Rs[0]*p0 + Rs[1]*p1 + Rs[2]*p2 + ts[0];
    pp[1] = Rs[3]*p0 + Rs[4]*p1 + Rs[5]*p2 + ts[1];
    pp[2] = Rs[6]*p0 + Rs[7]*p1 + Rs[8]*p2 + ts[2];
  }
  __syncthreads();
  for (int g = tid; g < 72; g += 256) ((float4*)pr)[432 + g] = ((float4*)vps)[g];  // vp back
  if (tid < 24) {
    int h = tid % 12;
    const float* s = (tid < 12) ? qk + 768 + h * 24 : qk + 1056 + h * 24;
    float a = 0.f;
    #pragma unroll
    for (int d = 0; d < 24; ++d) a += s[d] * s[d];
    float val = S3 * cf[h] * a;
    if (tid < 12) a2[h * 512 + j] = val; else b2[h * 512 + j] = val;
  }
  float s1 = S3 * INV_SQRT_QK;
  for (int o = tid; o < 672; o += 256) {
    int h = o / 56, d = o % 56;
    float s2 = -2.0f * S3 * cf[h];
    float aval = (d < 32) ? qk[h * 32 + d] * s1 : qk[768 + h * 24 + (d - 32)] * s2;
    float bval = (d < 32) ? qk[384 + h * 32 + d] : qk[1056 + h * 24 + (d - 32)];
    Ac[((size_t)h * 512 + j) * 56 + d] = aval;
    Bc[((size_t)h * 512 + j) * 56 + d] = bval;
  }
}

// ---------------- K2a: pair logits = S3 * z @ Wpair -> alphab[h][i][j] ----------------
// grid 2048 = i*4 + quarter(128 j-rows); 256 threads; c-split 2 per j-row.
__global__ __launch_bounds__(256) void k2a_pair(
    const float* __restrict__ z, const float* __restrict__ Wpair,
    float* __restrict__ alphab) {
  int blk = blockIdx.x;
  int i = blk >> 2, j0 = (blk & 3) * 128;
  int tid = threadIdx.x;
  __shared__ float zt[128 * 68];   // 34.8 KB
  __shared__ float wp[768];
  __shared__ float pl[12 * 128];   // 6 KB partials
  if (tid < 192) ((float4*)wp)[tid] = ((const float4*)Wpair)[tid];
  const float4* zsrc = (const float4*)(z + ((size_t)i * 512 + j0) * 64);
  for (int g = tid; g < 2048; g += 256) {
    int row = g >> 4, c4 = g & 15;
    ((float4*)(zt + row * 68))[c4] = zsrc[row * 16 + c4];
  }
  __syncthreads();
  int jl = tid & 127, half = tid >> 7;
  float acc[12];
  #pragma unroll
  for (int h = 0; h < 12; ++h) acc[h] = 0.f;
  const float4* zr = (const float4*)(zt + jl * 68) + half * 8;
  #pragma unroll
  for (int c4 = 0; c4 < 8; ++c4) {
    float4 zv = zr[c4];
    const float* w0 = wp + (half * 8 + c4) * 48;
    #pragma unroll
    for (int h = 0; h < 12; ++h)
      acc[h] += zv.x * w0[h] + zv.y * w0[12 + h] + zv.z * w0[24 + h] + zv.w * w0[36 + h];
  }
  if (half == 1) {
    #pragma unroll
    for (int h = 0; h < 12; ++h) pl[h * 128 + jl] = acc[h];
  }
  __syncthreads();
  if (half == 0) {
    #pragma unroll
    for (int h = 0; h < 12; ++h)
      alphab[(size_t)h * 262144 + (size_t)i * 512 + j0 + jl] = (acc[h] + pl[h * 128 + jl]) * S3;
  }
}

// ---------------- K2b: logits GEMM (K=56) + rank-1 terms + in-register softmax ----------------
__global__ __launch_bounds__(256) void k2b_logits(
    const float* __restrict__ Ac, const float* __restrict__ Bc,
    const float* __restrict__ a2, const float* __restrict__ b2,
    float* __restrict__ alphab) {
  int blk = blockIdx.x;
  int h = blk >> 5, i0 = (blk & 31) * 16;
  int tid = threadIdx.x;
  int ti = tid >> 5, tj = tid & 31;
  int r0 = 2 * ti;
  __shared__ float At[16 * 60];
  __shared__ float BtT[56 * 132];
  __shared__ float b2s[512];
  __shared__ float a2s[16];
  for (int g = tid; g < 224; g += 256) {
    int row = g / 14, u = g % 14;
    *(float4*)(At + row * 60 + u * 4) =
      *(const float4*)(Ac + ((size_t)h * 512 + i0 + row) * 56 + u * 4);
  }
  if (tid < 128) ((float4*)b2s)[tid] = ((const float4*)(b2 + h * 512))[tid];
  if (tid < 16) a2s[tid] = a2[h * 512 + i0 + tid];
  float lg[2][16];
  const size_t abase = (size_t)h * 262144;
  for (int jt = 0; jt < 4; ++jt) {
    int j0 = jt * 128;
    __syncthreads();
    for (int g = tid; g < 1792; g += 256) {
      int jl = g / 14, u = g % 14;
      float4 v = *(const float4*)(Bc + ((size_t)h * 512 + j0 + jl) * 56 + u * 4);
      BtT[(u * 4 + 0) * 132 + jl] = v.x;
      BtT[(u * 4 + 1) * 132 + jl] = v.y;
      BtT[(u * 4 + 2) * 132 + jl] = v.z;
      BtT[(u * 4 + 3) * 132 + jl] = v.w;
    }
    __syncthreads();
    float acc[2][4] = {{0.f,0.f,0.f,0.f},{0.f,0.f,0.f,0.f}};
    #pragma unroll 8
    for (int k = 0; k < 56; ++k) {
      float a0 = At[r0 * 60 + k], a1 = At[(r0 + 1) * 60 + k];
      float2 bA = *(const float2*)(BtT + k * 132 + 2 * tj);
      float2 bB = *(const float2*)(BtT + k * 132 + 64 + 2 * tj);
      acc[0][0] += a0 * bA.x; acc[0][1] += a0 * bA.y; acc[0][2] += a0 * bB.x; acc[0][3] += a0 * bB.y;
      acc[1][0] += a1 * bA.x; acc[1][1] += a1 * bA.y; acc[1][2] += a1 * bB.x; acc[1][3] += a1 * bB.y;
    }
    #pragma unroll
    for (int r = 0; r < 2; ++r) {
      int ig = i0 + r0 + r;
      const float* prow = alphab + abase + (size_t)ig * 512 + j0;
      int c0 = 2 * tj, c1 = 64 + 2 * tj;
      float arr = a2s[r0 + r];
      lg[r][jt*4+0] = acc[r][0] + prow[c0]     + arr + b2s[j0 + c0];
      lg[r][jt*4+1] = acc[r][1] + prow[c0 + 1] + arr + b2s[j0 + c0 + 1];
      lg[r][jt*4+2] = acc[r][2] + prow[c1]     + arr + b2s[j0 + c1];
      lg[r][jt*4+3] = acc[r][3] + prow[c1 + 1] + arr + b2s[j0 + c1 + 1];
    }
  }
  #pragma unroll
  for (int r = 0; r < 2; ++r) {
    float m = lg[r][0];
    #pragma unroll
    for (int u = 1; u < 16; ++u) m = fmaxf(m, lg[r][u]);
    #pragma unroll
    for (int s = 16; s > 0; s >>= 1) m = fmaxf(m, __shfl_xor(m, s));
    float ssum = 0.f;
    #pragma unroll
    for (int u = 0; u < 16; ++u) { lg[r][u] = __expf(lg[r][u] - m); ssum += lg[r][u]; }
    #pragma unroll
    for (int s = 16; s > 0; s >>= 1) ssum += __shfl_xor(ssum, s);
    float inv = 1.0f / ssum;
    float* orow = alphab + abase + (size_t)(i0 + r0 + r) * 512;
    #pragma unroll
    for (int jt = 0; jt < 4; ++jt) {
      *(float2*)(orow + jt * 128 + 2 * tj)      = make_float2(lg[r][jt*4+0] * inv, lg[r][jt*4+1] * inv);
      *(float2*)(orow + jt * 128 + 64 + 2 * tj) = make_float2(lg[r][jt*4+2] * inv, lg[r][jt*4+3] * inv);
    }
  }
}

// ---------------- K3a: feat_p2n = alpha[h][i][:] @ z[i] (512x64) ----------------
__global__ __launch_bounds__(256) void k3a_p2n(
    const float* __restrict__ alphab, const float* __restrict__ z,
    float* __restrict__ featb) {
  int i = blockIdx.x, tid = threadIdx.x;
  __shared__ float al[12 * 516];
  __shared__ float zt[64 * 68];
  for (int g = tid; g < 1536; g += 256) {
    int row = g >> 7, c4 = g & 127;
    *(float4*)(al + row * 516 + c4 * 4) =
      *(const float4*)(alphab + (size_t)row * 262144 + (size_t)i * 512 + c4 * 4);
  }
  int h = tid >> 4, c4 = tid & 15;
  float4 acc = {0.f, 0.f, 0.f, 0.f};
  const float4* zsrc = (const float4*)(z + (size_t)i * 512 * 64);
  for (int t8 = 0; t8 < 8; ++t8) {
    __syncthreads();
    for (int g = tid; g < 1024; g += 256) {
      int row = g >> 4, cc = g & 15;
      *(float4*)(&zt[row * 68 + cc * 4]) = zsrc[(t8 * 64 + row) * 16 + cc];
    }
    __syncthreads();
    if (tid < 192) {
      const float* ar = al + h * 516 + t8 * 64;
      #pragma unroll
      for (int k4 = 0; k4 < 16; ++k4) {
        float4 a4 = *(const float4*)(&ar[k4 * 4]);
        float4 z0 = *(const float4*)(&zt[(k4*4+0) * 68 + c4 * 4]);
        float4 z1 = *(const float4*)(&zt[(k4*4+1) * 68 + c4 * 4]);
        float4 z2 = *(const float4*)(&zt[(k4*4+2) * 68 + c4 * 4]);
        float4 z3 = *(const float4*)(&zt[(k4*4+3) * 68 + c4 * 4]);
        FMA4(acc, a4.x, z0); FMA4(acc, a4.y, z1); FMA4(acc, a4.z, z2); FMA4(acc, a4.w, z3);
      }
    }
  }
  if (tid < 192)
    *(float4*)(&featb[(size_t)i * 1440 + h * 64 + c4 * 4]) = acc;
}

// ---------------- K3b: feat_node + feat_spatial tiled GEMM per (h, i-tile-32) ----------------
__global__ __launch_bounds__(256) void k3b_nodevp(
    const float* __restrict__ alphab, const float* __restrict__ proj,
    const float* __restrict__ Rg, const float* __restrict__ tg,
    float* __restrict__ featb) {
  int b = blockIdx.x;
  int h = b >> 4, it = b & 15, i0 = it * 32;
  int tid = threadIdx.x;
  __shared__ float At[32 * 68];
  __shared__ float Bt[64 * 60];
  __shared__ float ag[32 * 24];
  int cg = tid % 14, rg = tid / 14;
  int c0 = cg * 4, r0 = rg * 2;
  float4 acc0 = {0,0,0,0}, acc1 = {0,0,0,0};
  for (int t8 = 0; t8 < 8; ++t8) {
    int j0 = t8 * 64;
    __syncthreads();
    for (int g = tid; g < 512; g += 256) {
      int row = g >> 4, cc = g & 15;
      *(float4*)(&At[row * 68 + cc * 4]) =
        *(const float4*)(alphab + (size_t)h * 262144 + (size_t)(i0 + row) * 512 + j0 + cc * 4);
    }
    for (int g = tid; g < 896; g += 256) {
      int row = g / 14, u = g % 14;
      const float* pr = proj + (size_t)(j0 + row) * PCOLS;
      float4 vv = (u < 8) ? *(const float4*)(&pr[1344 + h * 32 + u * 4])
                          : *(const float4*)(&pr[1728 + h * 24 + (u - 8) * 4]);
      int dst = (u < 8) ? u * 4 : 32 + (u - 8) * 4;
      *(float4*)(&Bt[row * 60 + dst]) = vv;
    }
    __syncthreads();
    if (rg < 16) {
      #pragma unroll 4
      for (int kk = 0; kk < 64; kk += 4) {
        float4 a0 = *(const float4*)(&At[(r0+0) * 68 + kk]);
        float4 a1 = *(const float4*)(&At[(r0+1) * 68 + kk]);
        float4 b0 = *(const float4*)(&Bt[(kk+0) * 60 + c0]);
        float4 b1 = *(const float4*)(&Bt[(kk+1) * 60 + c0]);
        float4 b2v = *(const float4*)(&Bt[(kk+2) * 60 + c0]);
        float4 b3 = *(const float4*)(&Bt[(kk+3) * 60 + c0]);
        FMA4(acc0, a0.x, b0); FMA4(acc0, a0.y, b1); FMA4(acc0, a0.z, b2v); FMA4(acc0, a0.w, b3);
        FMA4(acc1, a1.x, b0); FMA4(acc1, a1.y, b1); FMA4(acc1, a1.z, b2v); FMA4(acc1, a1.w, b3);
      }
    }
  }
  __syncthreads();
  if (rg < 16) {
    #pragma unroll
    for (int r = 0; r < 2; ++r) {
      float4 v = (r == 0) ? acc0 : acc1;
      int row = r0 + r;
      if (c0 < 32) {
        *(float4*)(&featb[(size_t)(i0 + row) * 1440 + 768 + h * 32 + c0]) = v;
      } else {
        int cc = c0 - 32;
        ag[row * 24 + cc + 0] = v.x; ag[row * 24 + cc + 1] = v.y;
        ag[row * 24 + cc + 2] = v.z; ag[row * 24 + cc + 3] = v.w;
      }
    }
  }
  __syncthreads();
  {
    int row = tid >> 3, p = tid & 7;
    const float* R  = Rg + (size_t)(i0 + row) * 9;
    const float* tt = tg + (size_t)(i0 + row) * 3;
    float d0 = ag[row * 24 + p * 3 + 0] - tt[0];
    float d1 = ag[row * 24 + p * 3 + 1] - tt[1];
    float d2 = ag[row * 24 + p * 3 + 2] - tt[2];
    float* o = featb + (size_t)(i0 + row) * 1440 + 1152 + h * 24 + p * 3;
    o[0] = R[0]*d0 + R[3]*d1 + R[6]*d2;
    o[1] = R[1]*d0 + R[4]*d1 + R[7]*d2;
    o[2] = R[2]*d0 + R[5]*d1 + R[8]*d2;
  }
}

// ---------------- K4: Wo GEMM + LN1 + MLP + LN2, float4 weight loads, k-split everywhere ----------------
// 256 blocks x 512 threads, 2 rows/block. All CUs busy; deep ILP on weight loads.
__global__ __launch_bounds__(512) void k4_mlp(
    const float* __restrict__ featb, const float* __restrict__ x,
    const float* __restrict__ Wo, const float* __restrict__ bo,
    const float* __restrict__ ln1s, const float* __restrict__ ln1o,
    const float* __restrict__ W1, const float* __restrict__ b1,
    const float* __restrict__ W2, const float* __restrict__ b2,
    const float* __restrict__ W3, const float* __restrict__ b3,
    const float* __restrict__ ln2s, const float* __restrict__ ln2o,
    float* __restrict__ out) {
  int i0 = blockIdx.x * 2;
  int tid = threadIdx.x;
  __shared__ float fs[2 * 1440];         // 11.5 KB
  __shared__ float4 part4[16][2][32];    // 16 KB
  __shared__ float stgA[2][128], stgB[2][128], stgC[2][128];  // 3 KB
  for (int g = tid; g < 720; g += 512)
    ((float4*)fs)[g] = ((const float4*)(featb + (size_t)i0 * 1440))[g];
  __syncthreads();
  // --- Wo GEMM: thread (q=tid>>5 k-chunk of 90, cg=tid&31 col4) ---
  int q = tid >> 5, cg = tid & 31;
  {
    float4 a0 = {0,0,0,0}, a1 = {0,0,0,0};
    int cb = q * 90;
    const float* f0 = fs + cb, *f1 = fs + 1440 + cb;
    #pragma unroll 6
    for (int c = 0; c < 90; ++c) {
      float4 w = *((const float4*)(Wo + (size_t)(cb + c) * 128) + cg);
      FMA4(a0, f0[c], w);
      FMA4(a1, f1[c], w);
    }
    part4[q][0][cg] = a0;
    part4[q][1][cg] = a1;
  }
  __syncthreads();
  if (tid < 64) {   // reduce 16 k-chunks -> y = Wo-out + bo + x
    int rr = tid >> 5, c = tid & 31;
    float4 s = part4[0][rr][c];
    #pragma unroll
    for (int k = 1; k < 16; ++k) ADD4(s, part4[k][rr][c]);
    float4 bo4 = ((const float4*)bo)[c];
    float4 xr4 = ((const float4*)(x + (size_t)(i0 + rr) * 128))[c];
    s.x += bo4.x + xr4.x; s.y += bo4.y + xr4.y; s.z += bo4.z + xr4.z; s.w += bo4.w + xr4.w;
    ((float4*)stgA[rr])[c] = s;
  }
  __syncthreads();
  // --- LN1: thread layout (q2=tid>>7, col=tid&127), rr=q2&1 (groups 2,3 duplicate) ---
  int q2 = tid >> 7, col = tid & 127, rr = q2 & 1;
  float x1;
  {
    float y = stgA[rr][col];
    float s1 = 0.f, s2 = 0.f;
    #pragma unroll 8
    for (int c4 = 0; c4 < 32; ++c4) {
      float4 v = ((const float4*)stgA[rr])[c4];
      s1 += v.x + v.y + v.z + v.w;
      s2 += v.x*v.x + v.y*v.y + v.z*v.z + v.w*v.w;
    }
    float mu = s1 * (1.f / 128.f);
    float var = s2 * (1.f / 128.f) - mu * mu;
    x1 = (y - mu) * rsqrtf(var + 1e-5f) * ln1s[col] + ln1o[col];
  }
  __syncthreads();
  stgB[rr][col] = x1;     // duplicate identical writes from q2 and q2+2: benign
  __syncthreads();
  // --- W1: thread (cg, sub=tid>>5: rr1=sub&1, kq=sub>>1 in 0..7), float4 loads ---
  int sub = tid >> 5, rr1 = sub & 1, kq = sub >> 1;
  {
    float4 aa = {0,0,0,0};
    int c0 = kq * 16;
    #pragma unroll
    for (int c = 0; c < 16; ++c) {
      float4 w = *((const float4*)(W1 + (size_t)(c0 + c) * 128) + cg);
      FMA4(aa, stgB[rr1][c0 + c], w);
    }
    part4[sub][0][cg] = aa;
  }
  __syncthreads();
  if (tid < 64) {
    int r2 = tid >> 5, c = tid & 31;
    float4 s = part4[r2][0][c];
    #pragma unroll
    for (int k = 1; k < 8; ++k) ADD4(s, part4[k * 2 + r2][0][c]);
    float4 b4 = ((const float4*)b1)[c];
    s.x = fmaxf(s.x + b4.x, 0.f); s.y = fmaxf(s.y + b4.y, 0.f);
    s.z = fmaxf(s.z + b4.z, 0.f); s.w = fmaxf(s.w + b4.w, 0.f);
    ((float4*)stgA[r2])[c] = s;
  }
  __syncthreads();
  // --- W2 ---
  {
    float4 aa = {0,0,0,0};
    int c0 = kq * 16;
    #pragma unroll
    for (int c = 0; c < 16; ++c) {
      float4 w = *((const float4*)(W2 + (size_t)(c0 + c) * 128) + cg);
      FMA4(aa, stgA[rr1][c0 + c], w);
    }
    part4[sub][0][cg] = aa;
  }
  __syncthreads();
  if (tid < 64) {
    int r2 = tid >> 5, c = tid & 31;
    float4 s = part4[r2][0][c];
    #pragma unroll
    for (int k = 1; k < 8; ++k) ADD4(s, part4[k * 2 + r2][0][c]);
    float4 b4 = ((const float4*)b2)[c];
    s.x = fmaxf(s.x + b4.x, 0.f); s.y = fmaxf(s.y + b4.y, 0.f);
    s.z = fmaxf(s.z + b4.z, 0.f); s.w = fmaxf(s.w + b4.w, 0.f);
    ((float4*)stgC[r2])[c] = s;
  }
  __syncthreads();
  // --- W3 ---
  {
    float4 aa = {0,0,0,0};
    int c0 = kq * 16;
    #pragma unroll
    for (int c = 0; c < 16; ++c) {
      float4 w = *((const float4*)(W3 + (size_t)(c0 + c) * 128) + cg);
      FMA4(aa, stgC[rr1][c0 + c], w);
    }
    part4[sub][0][cg] = aa;
  }
  __syncthreads();
  if (tid < 64) {
    int r2 = tid >> 5, c = tid & 31;
    float4 s = part4[r2][0][c];
    #pragma unroll
    for (int k = 1; k < 8; ++k) ADD4(s, part4[k * 2 + r2][0][c]);
    float4 b4 = ((const float4*)b3)[c];
    s.x += b4.x; s.y += b4.y; s.z += b4.z; s.w += b4.w;
    ((float4*)stgA[r2])[c] = s;    // mlp output (pre-residual)
  }
  __syncthreads();
  // --- residual + LN2 ---
  {
    float y2 = x1 + stgA[rr][col];
    stgC[rr][col] = y2;            // duplicate identical writes: benign
    __syncthreads();
    float s1 = 0.f, s2 = 0.f;
    #pragma unroll 8
    for (int c4 = 0; c4 < 32; ++c4) {
      float4 v = ((const float4*)stgC[rr])[c4];
      s1 += v.x + v.y + v.z + v.w;
      s2 += v.x*v.x + v.y*v.y + v.z*v.z + v.w*v.w;
    }
    float mu = s1 * (1.f / 128.f);
    float var = s2 * (1.f / 128.f) - mu * mu;
    if (q2 < 2)
      out[(size_t)(i0 + rr) * 128 + col] = (y2 - mu) * rsqrtf(var + 1e-5f) * ln2s[col] + ln2o[col];
  }
}

// ---------------- launch ----------------
extern "C" void kernel_launch(void* const* d_in, const int* in_sizes, int n_in,
                              void* d_out, int out_size, void* d_ws, size_t ws_size,
                              hipStream_t stream) {
  const float* Rg   = (const float*)d_in[0];
  const float* tg   = (const float*)d_in[1];
  const float* x    = (const float*)d_in[2];
  const float* z    = (const float*)d_in[3];
  // d_in[4] = mask (all true) -> no-op
  const float* Wq   = (const float*)d_in[5];
  const float* Wk   = (const float*)d_in[6];
  const float* Wpair= (const float*)d_in[7];
  const float* Wqp  = (const float*)d_in[8];
  const float* Wkp  = (const float*)d_in[9];
  const float* Wv   = (const float*)d_in[10];
  const float* Wvp  = (const float*)d_in[11];
  const float* sc   = (const float*)d_in[12];
  const float* Wo   = (const float*)d_in[13];
  const float* bo   = (const float*)d_in[14];
  const float* ln1s = (const float*)d_in[15];
  const float* ln1o = (const float*)d_in[16];
  const float* W1   = (const float*)d_in[17];
  const float* b1   = (const float*)d_in[18];
  const float* W2   = (const float*)d_in[19];
  const float* b2   = (const float*)d_in[20];
  const float* W3   = (const float*)d_in[21];
  const float* b3   = (const float*)d_in[22];
  const float* ln2s = (const float*)d_in[23];
  const float* ln2o = (const float*)d_in[24];

  float* ws = (float*)d_ws;
  float* proj   = ws;                        // 512*2016
  float* Ac     = proj + 512 * 2016;         // 12*512*56
  float* Bc     = Ac + 344064;
  float* a2     = Bc + 344064;
  float* b2v    = a2 + 6144;
  float* alphab = b2v + 6144;                // 12*512*512
  float* featb  = alphab + 3145728;          // 512*1440

  k1_gemm  <<<168, 256, 0, stream>>>(x, Wq, Wk, Wqp, Wkp, Wv, Wvp, proj);
  k1b_prep <<<512, 256, 0, stream>>>(Rg, tg, sc, proj, Ac, Bc, a2, b2v);
  k2a_pair <<<2048, 256, 0, stream>>>(z, Wpair, alphab);
  k2b_logits<<<384, 256, 0, stream>>>(Ac, Bc, a2, b2v, alphab);
  k3a_p2n  <<<512, 256, 0, stream>>>(alphab, z, featb);
  k3b_nodevp<<<192, 256, 0, stream>>>(alphab, proj, Rg, tg, featb);
  k4_mlp   <<<256, 512, 0, stream>>>(featb, x, Wo, bo, ln1s, ln1o,
                                     W1, b1, W2, b2, W3, b3, ln2s, ln2o, (float*)d_out);
}

// Round 7
// 129.801 us; speedup vs baseline: 6.7211x; 1.0933x over previous
//
#include <hip/hip_runtime.h>

// N=1, L=512, F=128, C=64, H=12, QK=32, Vd=32, Pq=8, Pv=8
// proj layout per row (2016 cols): [q 0..383][k 384..767][qp 768..1055][kp 1056..1343][v 1344..1727][vp 1728..2015]
#define PCOLS 2016

constexpr float INV_SQRT_QK = 0.17677669529663687f;  // 1/sqrt(32)
constexpr float S3          = 0.57735026918962576f;  // sqrt(1/3)

#define FMA4(acc, s, b) { acc.x += (s)*(b).x; acc.y += (s)*(b).y; acc.z += (s)*(b).z; acc.w += (s)*(b).w; }
#define ADD4(acc, b)    { acc.x += (b).x; acc.y += (b).y; acc.z += (b).z; acc.w += (b).w; }

// ---------------- K1: all projections as one tiled GEMM (LDS-staged W, float4 everywhere) ----------------
// grid 168 = 8 i-tiles x 21 o-tiles(96); 384 threads; thread = 4 rows x 4 cols
__global__ __launch_bounds__(384) void k1_gemm(
    const float* __restrict__ x,
    const float* __restrict__ Wq, const float* __restrict__ Wk,
    const float* __restrict__ Wqp, const float* __restrict__ Wkp,
    const float* __restrict__ Wv, const float* __restrict__ Wvp,
    float* __restrict__ proj) {
  int bt = blockIdx.x;
  int it = bt / 21, ot = bt % 21;
  int i0 = it * 64;
  int tid = threadIdx.x;
  __shared__ float xs[64 * 128];   // 32 KB
  __shared__ float ws[128 * 96];   // 48 KB
  const float* Wsec; int lofs, width;
  if (ot < 4)       { Wsec = Wq;  lofs = ot * 96;        width = 384; }
  else if (ot < 8)  { Wsec = Wk;  lofs = (ot - 4) * 96;  width = 384; }
  else if (ot < 11) { Wsec = Wqp; lofs = (ot - 8) * 96;  width = 288; }
  else if (ot < 14) { Wsec = Wkp; lofs = (ot - 11) * 96; width = 288; }
  else if (ot < 18) { Wsec = Wv;  lofs = (ot - 14) * 96; width = 384; }
  else              { Wsec = Wvp; lofs = (ot - 18) * 96; width = 288; }
  for (int g = tid; g < 2048; g += 384)
    *(float4*)(xs + (g >> 5) * 128 + (g & 31) * 4) =
      *(const float4*)(x + (size_t)(i0 + (g >> 5)) * 128 + (g & 31) * 4);
  for (int g = tid; g < 3072; g += 384) {
    int r = g / 24, u = g % 24;
    *(float4*)(ws + r * 96 + u * 4) = *(const float4*)(Wsec + (size_t)r * width + lofs + u * 4);
  }
  __syncthreads();
  int cg = tid % 24, tr = tid / 24;   // cg: col4, tr: 0..15 row-group of 4
  float4 acc0 = {0,0,0,0}, acc1 = {0,0,0,0}, acc2 = {0,0,0,0}, acc3 = {0,0,0,0};
  const float* x0 = xs + (tr * 4 + 0) * 128;
  const float* x1 = xs + (tr * 4 + 1) * 128;
  const float* x2 = xs + (tr * 4 + 2) * 128;
  const float* x3 = xs + (tr * 4 + 3) * 128;
  #pragma unroll 4
  for (int k = 0; k < 128; ++k) {
    float4 w = *(const float4*)(ws + k * 96 + cg * 4);
    FMA4(acc0, x0[k], w); FMA4(acc1, x1[k], w);
    FMA4(acc2, x2[k], w); FMA4(acc3, x3[k], w);
  }
  int gc = ot * 96 + cg * 4;
  *(float4*)(proj + (size_t)(i0 + tr * 4 + 0) * PCOLS + gc) = acc0;
  *(float4*)(proj + (size_t)(i0 + tr * 4 + 1) * PCOLS + gc) = acc1;
  *(float4*)(proj + (size_t)(i0 + tr * 4 + 2) * PCOLS + gc) = acc2;
  *(float4*)(proj + (size_t)(i0 + tr * 4 + 3) * PCOLS + gc) = acc3;
}

// ---------------- K1b: l2g transform + compact operands Ac (row-major) / BcT (transposed) ----------------
// Ac[h][i][56] = [q_h*(S3/sqrtQK) | qp_h*(-2*S3*cf_h)]; BcT[h][d][j] = [k_h | kp_h]
// a2[h][i] = S3*cf_h*|qp|^2 ; b2[h][j] = S3*cf_h*|kp|^2
__global__ __launch_bounds__(256) void k1b_prep(
    const float* __restrict__ Rg, const float* __restrict__ tg, const float* __restrict__ sc,
    float* __restrict__ proj, float* __restrict__ Ac, float* __restrict__ BcT,
    float* __restrict__ a2, float* __restrict__ b2) {
  int j = blockIdx.x, tid = threadIdx.x;
  __shared__ float qk[1344];   // [q][k][qp][kp]
  __shared__ float vps[288], Rs[9], ts[3], cf[12];
  float* pr = proj + (size_t)j * PCOLS;
  const float4* pr4 = (const float4*)pr;
  for (int g = tid; g < 336; g += 256) ((float4*)qk)[g] = pr4[g];
  for (int g = tid; g < 72; g += 256) ((float4*)vps)[g] = pr4[432 + g];
  if (tid < 9) Rs[tid] = Rg[j * 9 + tid];
  else if (tid < 12) ts[tid - 9] = tg[j * 3 + tid - 9];
  else if (tid < 24) cf[tid - 12] = -log1pf(__expf(sc[tid - 12])) * (1.0f / 12.0f);
  __syncthreads();
  for (int p = tid; p < 288; p += 256) {
    int sec = p / 96, m = p % 96;
    float* P = (sec == 0) ? qk + 768 : (sec == 1) ? qk + 1056 : vps;
    float* pp = P + m * 3;
    float p0 = pp[0], p1 = pp[1], p2 = pp[2];
    pp[0] = Rs[0]*p0 + Rs[1]*p1 + Rs[2]*p2 + ts[0];
    pp[1] = Rs[3]*p0 + Rs[4]*p1 + Rs[5]*p2 + ts[1];
    pp[2] = Rs[6]*p0 + Rs[7]*p1 + Rs[8]*p2 + ts[2];
  }
  __syncthreads();
  for (int g = tid; g < 72; g += 256) ((float4*)pr)[432 + g] = ((float4*)vps)[g];  // vp back
  if (tid < 24) {
    int h = tid % 12;
    const float* s = (tid < 12) ? qk + 768 + h * 24 : qk + 1056 + h * 24;
    float a = 0.f;
    #pragma unroll
    for (int d = 0; d < 24; ++d) a += s[d] * s[d];
    float val = S3 * cf[h] * a;
    if (tid < 12) a2[h * 512 + j] = val; else b2[h * 512 + j] = val;
  }
  float s1 = S3 * INV_SQRT_QK;
  for (int o = tid; o < 672; o += 256) {
    int h = o / 56, d = o % 56;
    float s2 = -2.0f * S3 * cf[h];
    float aval = (d < 32) ? qk[h * 32 + d] * s1 : qk[768 + h * 24 + (d - 32)] * s2;
    float bval = (d < 32) ? qk[384 + h * 32 + d] : qk[1056 + h * 24 + (d - 32)];
    Ac[((size_t)h * 512 + j) * 56 + d] = aval;
    BcT[((size_t)h * 56 + d) * 512 + j] = bval;
  }
}

// ---------------- K2a: pair logits = S3 * z @ Wpair -> alphab[h][i][j] ----------------
__global__ __launch_bounds__(256) void k2a_pair(
    const float* __restrict__ z, const float* __restrict__ Wpair,
    float* __restrict__ alphab) {
  int blk = blockIdx.x;
  int i = blk >> 2, j0 = (blk & 3) * 128;
  int tid = threadIdx.x;
  __shared__ float zt[128 * 68];
  __shared__ float wp[768];
  __shared__ float pl[12 * 128];
  if (tid < 192) ((float4*)wp)[tid] = ((const float4*)Wpair)[tid];
  const float4* zsrc = (const float4*)(z + ((size_t)i * 512 + j0) * 64);
  for (int g = tid; g < 2048; g += 256) {
    int row = g >> 4, c4 = g & 15;
    ((float4*)(zt + row * 68))[c4] = zsrc[row * 16 + c4];
  }
  __syncthreads();
  int jl = tid & 127, half = tid >> 7;
  float acc[12];
  #pragma unroll
  for (int h = 0; h < 12; ++h) acc[h] = 0.f;
  const float4* zr = (const float4*)(zt + jl * 68) + half * 8;
  #pragma unroll
  for (int c4 = 0; c4 < 8; ++c4) {
    float4 zv = zr[c4];
    const float* w0 = wp + (half * 8 + c4) * 48;
    #pragma unroll
    for (int h = 0; h < 12; ++h)
      acc[h] += zv.x * w0[h] + zv.y * w0[12 + h] + zv.z * w0[24 + h] + zv.w * w0[36 + h];
  }
  if (half == 1) {
    #pragma unroll
    for (int h = 0; h < 12; ++h) pl[h * 128 + jl] = acc[h];
  }
  __syncthreads();
  if (half == 0) {
    #pragma unroll
    for (int h = 0; h < 12; ++h)
      alphab[(size_t)h * 262144 + (size_t)i * 512 + j0 + jl] = (acc[h] + pl[h * 128 + jl]) * S3;
  }
}

// ---------------- K2b: logits GEMM + softmax + fused node/vp aggregation + g2l ----------------
// grid 384 = h*32 + it(16 rows); 256 threads. Phase1: logits (K=56) + in-register softmax.
// Phase2: alpha in LDS -> feat_node/feat_spatial GEMM (16x56, K=512) + g2l epilogue.
__global__ __launch_bounds__(256) void k2b_logits(
    const float* __restrict__ Ac, const float* __restrict__ BcT,
    const float* __restrict__ a2, const float* __restrict__ b2,
    const float* __restrict__ proj, const float* __restrict__ Rg, const float* __restrict__ tg,
    float* __restrict__ alphab, float* __restrict__ featb) {
  int blk = blockIdx.x;
  int h = blk >> 5, i0 = (blk & 31) * 16;
  int tid = threadIdx.x;
  int ti = tid >> 5, tj = tid & 31;
  int r0 = 2 * ti;
  __shared__ float smem[12480];          // 49.9 KB, phase-unioned
  float* At  = smem;                     // [16][60]   phase 1
  float* BtT = smem + 960;               // [56][132]  phase 1
  float* b2s = smem + 8352;              // [512]      phase 1
  float* a2s = smem + 8864;              // [16]       phase 1
  float* als = smem;                     // [16][516]  phase 2
  float* Bt  = smem + 8256;              // [64][60]   phase 2
  float* ag  = smem + 12096;             // [16][24]   phase 2
  for (int g = tid; g < 224; g += 256) {
    int row = g / 14, u = g % 14;
    *(float4*)(At + row * 60 + u * 4) =
      *(const float4*)(Ac + ((size_t)h * 512 + i0 + row) * 56 + u * 4);
  }
  if (tid < 128) ((float4*)b2s)[tid] = ((const float4*)(b2 + h * 512))[tid];
  if (tid < 16) a2s[tid] = a2[h * 512 + i0 + tid];
  float lg[2][16];
  const size_t abase = (size_t)h * 262144;
  for (int jt = 0; jt < 4; ++jt) {
    int j0 = jt * 128;
    __syncthreads();
    // stage BtT [56][128] from BcT with float4 (no scalar transpose)
    for (int g = tid; g < 1792; g += 256) {
      int k = g >> 5, c4 = g & 31;
      *(float4*)(BtT + k * 132 + c4 * 4) =
        *(const float4*)(BcT + ((size_t)h * 56 + k) * 512 + j0 + c4 * 4);
    }
    __syncthreads();
    float acc[2][4] = {{0.f,0.f,0.f,0.f},{0.f,0.f,0.f,0.f}};
    #pragma unroll 8
    for (int k = 0; k < 56; ++k) {
      float a0 = At[r0 * 60 + k], a1 = At[(r0 + 1) * 60 + k];
      float2 bA = *(const float2*)(BtT + k * 132 + 2 * tj);
      float2 bB = *(const float2*)(BtT + k * 132 + 64 + 2 * tj);
      acc[0][0] += a0 * bA.x; acc[0][1] += a0 * bA.y; acc[0][2] += a0 * bB.x; acc[0][3] += a0 * bB.y;
      acc[1][0] += a1 * bA.x; acc[1][1] += a1 * bA.y; acc[1][2] += a1 * bB.x; acc[1][3] += a1 * bB.y;
    }
    #pragma unroll
    for (int r = 0; r < 2; ++r) {
      int ig = i0 + r0 + r;
      const float* prow = alphab + abase + (size_t)ig * 512 + j0;
      int c0 = 2 * tj, c1 = 64 + 2 * tj;
      float arr = a2s[r0 + r];
      lg[r][jt*4+0] = acc[r][0] + prow[c0]     + arr + b2s[j0 + c0];
      lg[r][jt*4+1] = acc[r][1] + prow[c0 + 1] + arr + b2s[j0 + c0 + 1];
      lg[r][jt*4+2] = acc[r][2] + prow[c1]     + arr + b2s[j0 + c1];
      lg[r][jt*4+3] = acc[r][3] + prow[c1 + 1] + arr + b2s[j0 + c1 + 1];
    }
  }
  __syncthreads();   // all BtT/At/b2s reads done before als overwrites them
  // softmax (registers + 32-lane shfl), write alpha to global AND LDS
  #pragma unroll
  for (int r = 0; r < 2; ++r) {
    float m = lg[r][0];
    #pragma unroll
    for (int u = 1; u < 16; ++u) m = fmaxf(m, lg[r][u]);
    #pragma unroll
    for (int s = 16; s > 0; s >>= 1) m = fmaxf(m, __shfl_xor(m, s));
    float ssum = 0.f;
    #pragma unroll
    for (int u = 0; u < 16; ++u) { lg[r][u] = __expf(lg[r][u] - m); ssum += lg[r][u]; }
    #pragma unroll
    for (int s = 16; s > 0; s >>= 1) ssum += __shfl_xor(ssum, s);
    float inv = 1.0f / ssum;
    int row = r0 + r;
    float* orow = alphab + abase + (size_t)(i0 + row) * 512;
    #pragma unroll
    for (int jt = 0; jt < 4; ++jt) {
      float2 vA = make_float2(lg[r][jt*4+0] * inv, lg[r][jt*4+1] * inv);
      float2 vB = make_float2(lg[r][jt*4+2] * inv, lg[r][jt*4+3] * inv);
      *(float2*)(orow + jt * 128 + 2 * tj)      = vA;
      *(float2*)(orow + jt * 128 + 64 + 2 * tj) = vB;
      *(float2*)(als + row * 516 + jt * 128 + 2 * tj)      = vA;
      *(float2*)(als + row * 516 + jt * 128 + 64 + 2 * tj) = vB;
    }
  }
  // ---- phase 2: node/vp aggregation (16 rows x 56 cols, K=512) ----
  int cg2 = tid % 14, rg = tid / 14;      // rg 0..18, active < 16
  int c0 = cg2 * 4;
  float4 acc4 = {0,0,0,0};
  for (int t8 = 0; t8 < 8; ++t8) {
    int j0 = t8 * 64;
    __syncthreads();
    for (int g = tid; g < 896; g += 256) {
      int row = g / 14, u = g % 14;
      const float* pr = proj + (size_t)(j0 + row) * PCOLS;
      float4 vv = (u < 8) ? *(const float4*)(&pr[1344 + h * 32 + u * 4])
                          : *(const float4*)(&pr[1728 + h * 24 + (u - 8) * 4]);
      int dst = (u < 8) ? u * 4 : 32 + (u - 8) * 4;
      *(float4*)(Bt + row * 60 + dst) = vv;
    }
    __syncthreads();
    if (rg < 16) {
      const float* arow = als + rg * 516 + j0;
      #pragma unroll 8
      for (int kk = 0; kk < 64; ++kk) {
        float a = arow[kk];
        float4 b = *(const float4*)(Bt + kk * 60 + c0);
        FMA4(acc4, a, b);
      }
    }
  }
  __syncthreads();
  if (rg < 16) {
    if (c0 < 32) {
      *(float4*)(&featb[(size_t)(i0 + rg) * 1440 + 768 + h * 32 + c0]) = acc4;
    } else {
      int cc = c0 - 32;
      ag[rg * 24 + cc + 0] = acc4.x; ag[rg * 24 + cc + 1] = acc4.y;
      ag[rg * 24 + cc + 2] = acc4.z; ag[rg * 24 + cc + 3] = acc4.w;
    }
  }
  __syncthreads();
  if (tid < 128) {   // g2l: 16 rows x 8 points
    int row = tid >> 3, p = tid & 7;
    const float* R  = Rg + (size_t)(i0 + row) * 9;
    const float* tt = tg + (size_t)(i0 + row) * 3;
    float d0 = ag[row * 24 + p * 3 + 0] - tt[0];
    float d1 = ag[row * 24 + p * 3 + 1] - tt[1];
    float d2 = ag[row * 24 + p * 3 + 2] - tt[2];
    float* o = featb + (size_t)(i0 + row) * 1440 + 1152 + h * 24 + p * 3;
    o[0] = R[0]*d0 + R[3]*d1 + R[6]*d2;
    o[1] = R[1]*d0 + R[4]*d1 + R[7]*d2;
    o[2] = R[2]*d0 + R[5]*d1 + R[8]*d2;
  }
}

// ---------------- K3a: feat_p2n = alpha[h][i][:] @ z[i] (512x64) ----------------
__global__ __launch_bounds__(256) void k3a_p2n(
    const float* __restrict__ alphab, const float* __restrict__ z,
    float* __restrict__ featb) {
  int i = blockIdx.x, tid = threadIdx.x;
  __shared__ float al[12 * 516];
  __shared__ float zt[64 * 68];
  for (int g = tid; g < 1536; g += 256) {
    int row = g >> 7, c4 = g & 127;
    *(float4*)(al + row * 516 + c4 * 4) =
      *(const float4*)(alphab + (size_t)row * 262144 + (size_t)i * 512 + c4 * 4);
  }
  int h = tid >> 4, c4 = tid & 15;
  float4 acc = {0.f, 0.f, 0.f, 0.f};
  const float4* zsrc = (const float4*)(z + (size_t)i * 512 * 64);
  for (int t8 = 0; t8 < 8; ++t8) {
    __syncthreads();
    for (int g = tid; g < 1024; g += 256) {
      int row = g >> 4, cc = g & 15;
      *(float4*)(&zt[row * 68 + cc * 4]) = zsrc[(t8 * 64 + row) * 16 + cc];
    }
    __syncthreads();
    if (tid < 192) {
      const float* ar = al + h * 516 + t8 * 64;
      #pragma unroll
      for (int k4 = 0; k4 < 16; ++k4) {
        float4 a4 = *(const float4*)(&ar[k4 * 4]);
        float4 z0 = *(const float4*)(&zt[(k4*4+0) * 68 + c4 * 4]);
        float4 z1 = *(const float4*)(&zt[(k4*4+1) * 68 + c4 * 4]);
        float4 z2 = *(const float4*)(&zt[(k4*4+2) * 68 + c4 * 4]);
        float4 z3 = *(const float4*)(&zt[(k4*4+3) * 68 + c4 * 4]);
        FMA4(acc, a4.x, z0); FMA4(acc, a4.y, z1); FMA4(acc, a4.z, z2); FMA4(acc, a4.w, z3);
      }
    }
  }
  if (tid < 192)
    *(float4*)(&featb[(size_t)i * 1440 + h * 64 + c4 * 4]) = acc;
}

// ---------------- K4: Wo GEMM + LN1 + MLP + LN2 ----------------
__global__ __launch_bounds__(512) void k4_mlp(
    const float* __restrict__ featb, const float* __restrict__ x,
    const float* __restrict__ Wo, const float* __restrict__ bo,
    const float* __restrict__ ln1s, const float* __restrict__ ln1o,
    const float* __restrict__ W1, const float* __restrict__ b1,
    const float* __restrict__ W2, const float* __restrict__ b2,
    const float* __restrict__ W3, const float* __restrict__ b3,
    const float* __restrict__ ln2s, const float* __restrict__ ln2o,
    float* __restrict__ out) {
  int i0 = blockIdx.x * 2;
  int tid = threadIdx.x;
  __shared__ float fs[2 * 1440];
  __shared__ float4 part4[16][2][32];
  __shared__ float stgA[2][128], stgB[2][128], stgC[2][128];
  for (int g = tid; g < 720; g += 512)
    ((float4*)fs)[g] = ((const float4*)(featb + (size_t)i0 * 1440))[g];
  __syncthreads();
  int q = tid >> 5, cg = tid & 31;
  {
    float4 a0 = {0,0,0,0}, a1 = {0,0,0,0};
    int cb = q * 90;
    const float* f0 = fs + cb, *f1 = fs + 1440 + cb;
    #pragma unroll 6
    for (int c = 0; c < 90; ++c) {
      float4 w = *((const float4*)(Wo + (size_t)(cb + c) * 128) + cg);
      FMA4(a0, f0[c], w);
      FMA4(a1, f1[c], w);
    }
    part4[q][0][cg] = a0;
    part4[q][1][cg] = a1;
  }
  __syncthreads();
  if (tid < 64) {
    int rr = tid >> 5, c = tid & 31;
    float4 s = part4[0][rr][c];
    #pragma unroll
    for (int k = 1; k < 16; ++k) ADD4(s, part4[k][rr][c]);
    float4 bo4 = ((const float4*)bo)[c];
    float4 xr4 = ((const float4*)(x + (size_t)(i0 + rr) * 128))[c];
    s.x += bo4.x + xr4.x; s.y += bo4.y + xr4.y; s.z += bo4.z + xr4.z; s.w += bo4.w + xr4.w;
    ((float4*)stgA[rr])[c] = s;
  }
  __syncthreads();
  int q2 = tid >> 7, col = tid & 127, rr = q2 & 1;
  float x1;
  {
    float y = stgA[rr][col];
    float s1 = 0.f, s2 = 0.f;
    #pragma unroll 8
    for (int c4 = 0; c4 < 32; ++c4) {
      float4 v = ((const float4*)stgA[rr])[c4];
      s1 += v.x + v.y + v.z + v.w;
      s2 += v.x*v.x + v.y*v.y + v.z*v.z + v.w*v.w;
    }
    float mu = s1 * (1.f / 128.f);
    float var = s2 * (1.f / 128.f) - mu * mu;
    x1 = (y - mu) * rsqrtf(var + 1e-5f) * ln1s[col] + ln1o[col];
  }
  __syncthreads();
  stgB[rr][col] = x1;
  __syncthreads();
  int sub = tid >> 5, rr1 = sub & 1, kq = sub >> 1;
  {
    float4 aa = {0,0,0,0};
    int c0 = kq * 16;
    #pragma unroll
    for (int c = 0; c < 16; ++c) {
      float4 w = *((const float4*)(W1 + (size_t)(c0 + c) * 128) + cg);
      FMA4(aa, stgB[rr1][c0 + c], w);
    }
    part4[sub][0][cg] = aa;
  }
  __syncthreads();
  if (tid < 64) {
    int r2 = tid >> 5, c = tid & 31;
    float4 s = part4[r2][0][c];
    #pragma unroll
    for (int k = 1; k < 8; ++k) ADD4(s, part4[k * 2 + r2][0][c]);
    float4 b4 = ((const float4*)b1)[c];
    s.x = fmaxf(s.x + b4.x, 0.f); s.y = fmaxf(s.y + b4.y, 0.f);
    s.z = fmaxf(s.z + b4.z, 0.f); s.w = fmaxf(s.w + b4.w, 0.f);
    ((float4*)stgA[r2])[c] = s;
  }
  __syncthreads();
  {
    float4 aa = {0,0,0,0};
    int c0 = kq * 16;
    #pragma unroll
    for (int c = 0; c < 16; ++c) {
      float4 w = *((const float4*)(W2 + (size_t)(c0 + c) * 128) + cg);
      FMA4(aa, stgA[rr1][c0 + c], w);
    }
    part4[sub][0][cg] = aa;
  }
  __syncthreads();
  if (tid < 64) {
    int r2 = tid >> 5, c = tid & 31;
    float4 s = part4[r2][0][c];
    #pragma unroll
    for (int k = 1; k < 8; ++k) ADD4(s, part4[k * 2 + r2][0][c]);
    float4 b4 = ((const float4*)b2)[c];
    s.x = fmaxf(s.x + b4.x, 0.f); s.y = fmaxf(s.y + b4.y, 0.f);
    s.z = fmaxf(s.z + b4.z, 0.f); s.w = fmaxf(s.w + b4.w, 0.f);
    ((float4*)stgC[r2])[c] = s;
  }
  __syncthreads();
  {
    float4 aa = {0,0,0,0};
    int c0 = kq * 16;
    #pragma unroll
    for (int c = 0; c < 16; ++c) {
      float4 w = *((const float4*)(W3 + (size_t)(c0 + c) * 128) + cg);
      FMA4(aa, stgC[rr1][c0 + c], w);
    }
    part4[sub][0][cg] = aa;
  }
  __syncthreads();
  if (tid < 64) {
    int r2 = tid >> 5, c = tid & 31;
    float4 s = part4[r2][0][c];
    #pragma unroll
    for (int k = 1; k < 8; ++k) ADD4(s, part4[k * 2 + r2][0][c]);
    float4 b4 = ((const float4*)b3)[c];
    s.x += b4.x; s.y += b4.y; s.z += b4.z; s.w += b4.w;
    ((float4*)stgA[r2])[c] = s;
  }
  __syncthreads();
  {
    float y2 = x1 + stgA[rr][col];
    stgC[rr][col] = y2;
    __syncthreads();
    float s1 = 0.f, s2 = 0.f;
    #pragma unroll 8
    for (int c4 = 0; c4 < 32; ++c4) {
      float4 v = ((const float4*)stgC[rr])[c4];
      s1 += v.x + v.y + v.z + v.w;
      s2 += v.x*v.x + v.y*v.y + v.z*v.z + v.w*v.w;
    }
    float mu = s1 * (1.f / 128.f);
    float var = s2 * (1.f / 128.f) - mu * mu;
    if (q2 < 2)
      out[(size_t)(i0 + rr) * 128 + col] = (y2 - mu) * rsqrtf(var + 1e-5f) * ln2s[col] + ln2o[col];
  }
}

// ---------------- launch ----------------
extern "C" void kernel_launch(void* const* d_in, const int* in_sizes, int n_in,
                              void* d_out, int out_size, void* d_ws, size_t ws_size,
                              hipStream_t stream) {
  const float* Rg   = (const float*)d_in[0];
  const float* tg   = (const float*)d_in[1];
  const float* x    = (const float*)d_in[2];
  const float* z    = (const float*)d_in[3];
  // d_in[4] = mask (all true) -> no-op
  const float* Wq   = (const float*)d_in[5];
  const float* Wk   = (const float*)d_in[6];
  const float* Wpair= (const float*)d_in[7];
  const float* Wqp  = (const float*)d_in[8];
  const float* Wkp  = (const float*)d_in[9];
  const float* Wv   = (const float*)d_in[10];
  const float* Wvp  = (const float*)d_in[11];
  const float* sc   = (const float*)d_in[12];
  const float* Wo   = (const float*)d_in[13];
  const float* bo   = (const float*)d_in[14];
  const float* ln1s = (const float*)d_in[15];
  const float* ln1o = (const float*)d_in[16];
  const float* W1   = (const float*)d_in[17];
  const float* b1   = (const float*)d_in[18];
  const float* W2   = (const float*)d_in[19];
  const float* b2   = (const float*)d_in[20];
  const float* W3   = (const float*)d_in[21];
  const float* b3   = (const float*)d_in[22];
  const float* ln2s = (const float*)d_in[23];
  const float* ln2o = (const float*)d_in[24];

  float* ws = (float*)d_ws;
  float* proj   = ws;                        // 512*2016
  float* Ac     = proj + 512 * 2016;         // 12*512*56
  float* BcT    = Ac + 344064;               // 12*56*512 (transposed)
  float* a2     = BcT + 344064;
  float* b2v    = a2 + 6144;
  float* alphab = b2v + 6144;                // 12*512*512
  float* featb  = alphab + 3145728;          // 512*1440

  k1_gemm  <<<168, 384, 0, stream>>>(x, Wq, Wk, Wqp, Wkp, Wv, Wvp, proj);
  k1b_prep <<<512, 256, 0, stream>>>(Rg, tg, sc, proj, Ac, BcT, a2, b2v);
  k2a_pair <<<2048, 256, 0, stream>>>(z, Wpair, alphab);
  k2b_logits<<<384, 256, 0, stream>>>(Ac, BcT, a2, b2v, proj, Rg, tg, alphab, featb);
  k3a_p2n  <<<512, 256, 0, stream>>>(alphab, z, featb);
  k4_mlp   <<<256, 512, 0, stream>>>(featb, x, Wo, bo, ln1s, ln1o,
                                     W1, b1, W2, b2, W3, b3, ln2s, ln2o, (float*)d_out);
}

// Round 8
// 120.143 us; speedup vs baseline: 7.2614x; 1.0804x over previous
//
#include <hip/hip_runtime.h>

// N=1, L=512, F=128, C=64, H=12, QK=32, Vd=32, Pq=8, Pv=8
// proj layout per row (2016 cols): [q 0..383][k 384..767][qp 768..1055][kp 1056..1343][v 1344..1727][vp 1728..2015]
#define PCOLS 2016

constexpr float INV_SQRT_QK = 0.17677669529663687f;  // 1/sqrt(32)
constexpr float S3          = 0.57735026918962576f;  // sqrt(1/3)

#define FMA4(acc, s, b) { acc.x += (s)*(b).x; acc.y += (s)*(b).y; acc.z += (s)*(b).z; acc.w += (s)*(b).w; }
#define ADD4(acc, b)    { acc.x += (b).x; acc.y += (b).y; acc.z += (b).z; acc.w += (b).w; }

// ---------------- K1: all projections as one tiled GEMM (LDS-staged W) ----------------
__global__ __launch_bounds__(384) void k1_gemm(
    const float* __restrict__ x,
    const float* __restrict__ Wq, const float* __restrict__ Wk,
    const float* __restrict__ Wqp, const float* __restrict__ Wkp,
    const float* __restrict__ Wv, const float* __restrict__ Wvp,
    float* __restrict__ proj) {
  int bt = blockIdx.x;
  int it = bt / 21, ot = bt % 21;
  int i0 = it * 64;
  int tid = threadIdx.x;
  __shared__ float xs[64 * 128];   // 32 KB
  __shared__ float ws[128 * 96];   // 48 KB
  const float* Wsec; int lofs, width;
  if (ot < 4)       { Wsec = Wq;  lofs = ot * 96;        width = 384; }
  else if (ot < 8)  { Wsec = Wk;  lofs = (ot - 4) * 96;  width = 384; }
  else if (ot < 11) { Wsec = Wqp; lofs = (ot - 8) * 96;  width = 288; }
  else if (ot < 14) { Wsec = Wkp; lofs = (ot - 11) * 96; width = 288; }
  else if (ot < 18) { Wsec = Wv;  lofs = (ot - 14) * 96; width = 384; }
  else              { Wsec = Wvp; lofs = (ot - 18) * 96; width = 288; }
  for (int g = tid; g < 2048; g += 384)
    *(float4*)(xs + (g >> 5) * 128 + (g & 31) * 4) =
      *(const float4*)(x + (size_t)(i0 + (g >> 5)) * 128 + (g & 31) * 4);
  for (int g = tid; g < 3072; g += 384) {
    int r = g / 24, u = g % 24;
    *(float4*)(ws + r * 96 + u * 4) = *(const float4*)(Wsec + (size_t)r * width + lofs + u * 4);
  }
  __syncthreads();
  int cg = tid % 24, tr = tid / 24;
  float4 acc0 = {0,0,0,0}, acc1 = {0,0,0,0}, acc2 = {0,0,0,0}, acc3 = {0,0,0,0};
  const float* x0 = xs + (tr * 4 + 0) * 128;
  const float* x1 = xs + (tr * 4 + 1) * 128;
  const float* x2 = xs + (tr * 4 + 2) * 128;
  const float* x3 = xs + (tr * 4 + 3) * 128;
  #pragma unroll 4
  for (int k = 0; k < 128; ++k) {
    float4 w = *(const float4*)(ws + k * 96 + cg * 4);
    FMA4(acc0, x0[k], w); FMA4(acc1, x1[k], w);
    FMA4(acc2, x2[k], w); FMA4(acc3, x3[k], w);
  }
  int gc = ot * 96 + cg * 4;
  *(float4*)(proj + (size_t)(i0 + tr * 4 + 0) * PCOLS + gc) = acc0;
  *(float4*)(proj + (size_t)(i0 + tr * 4 + 1) * PCOLS + gc) = acc1;
  *(float4*)(proj + (size_t)(i0 + tr * 4 + 2) * PCOLS + gc) = acc2;
  *(float4*)(proj + (size_t)(i0 + tr * 4 + 3) * PCOLS + gc) = acc3;
}

// ---------------- K1b: l2g transform + compact operands Ac / BcT / a2 / b2 ----------------
__global__ __launch_bounds__(256) void k1b_prep(
    const float* __restrict__ Rg, const float* __restrict__ tg, const float* __restrict__ sc,
    float* __restrict__ proj, float* __restrict__ Ac, float* __restrict__ BcT,
    float* __restrict__ a2, float* __restrict__ b2) {
  int j = blockIdx.x, tid = threadIdx.x;
  __shared__ float qk[1344];
  __shared__ float vps[288], Rs[9], ts[3], cf[12];
  float* pr = proj + (size_t)j * PCOLS;
  const float4* pr4 = (const float4*)pr;
  for (int g = tid; g < 336; g += 256) ((float4*)qk)[g] = pr4[g];
  for (int g = tid; g < 72; g += 256) ((float4*)vps)[g] = pr4[432 + g];
  if (tid < 9) Rs[tid] = Rg[j * 9 + tid];
  else if (tid < 12) ts[tid - 9] = tg[j * 3 + tid - 9];
  else if (tid < 24) cf[tid - 12] = -log1pf(__expf(sc[tid - 12])) * (1.0f / 12.0f);
  __syncthreads();
  for (int p = tid; p < 288; p += 256) {
    int sec = p / 96, m = p % 96;
    float* P = (sec == 0) ? qk + 768 : (sec == 1) ? qk + 1056 : vps;
    float* pp = P + m * 3;
    float p0 = pp[0], p1 = pp[1], p2 = pp[2];
    pp[0] = Rs[0]*p0 + Rs[1]*p1 + Rs[2]*p2 + ts[0];
    pp[1] = Rs[3]*p0 + Rs[4]*p1 + Rs[5]*p2 + ts[1];
    pp[2] = Rs[6]*p0 + Rs[7]*p1 + Rs[8]*p2 + ts[2];
  }
  __syncthreads();
  for (int g = tid; g < 72; g += 256) ((float4*)pr)[432 + g] = ((float4*)vps)[g];
  if (tid < 24) {
    int h = tid % 12;
    const float* s = (tid < 12) ? qk + 768 + h * 24 : qk + 1056 + h * 24;
    float a = 0.f;
    #pragma unroll
    for (int d = 0; d < 24; ++d) a += s[d] * s[d];
    float val = S3 * cf[h] * a;
    if (tid < 12) a2[h * 512 + j] = val; else b2[h * 512 + j] = val;
  }
  float s1 = S3 * INV_SQRT_QK;
  for (int o = tid; o < 672; o += 256) {
    int h = o / 56, d = o % 56;
    float s2 = -2.0f * S3 * cf[h];
    float aval = (d < 32) ? qk[h * 32 + d] * s1 : qk[768 + h * 24 + (d - 32)] * s2;
    float bval = (d < 32) ? qk[384 + h * 32 + d] : qk[1056 + h * 24 + (d - 32)];
    Ac[((size_t)h * 512 + j) * 56 + d] = aval;
    BcT[((size_t)h * 56 + d) * 512 + j] = bval;
  }
}

// ---------------- K2a: pair logits = S3 * z @ Wpair -> alphab[h][i][j] ----------------
__global__ __launch_bounds__(256) void k2a_pair(
    const float* __restrict__ z, const float* __restrict__ Wpair,
    float* __restrict__ alphab) {
  int blk = blockIdx.x;
  int i = blk >> 2, j0 = (blk & 3) * 128;
  int tid = threadIdx.x;
  __shared__ float zt[128 * 68];
  __shared__ float wp[768];
  __shared__ float pl[12 * 128];
  if (tid < 192) ((float4*)wp)[tid] = ((const float4*)Wpair)[tid];
  const float4* zsrc = (const float4*)(z + ((size_t)i * 512 + j0) * 64);
  for (int g = tid; g < 2048; g += 256) {
    int row = g >> 4, c4 = g & 15;
    ((float4*)(zt + row * 68))[c4] = zsrc[row * 16 + c4];
  }
  __syncthreads();
  int jl = tid & 127, half = tid >> 7;
  float acc[12];
  #pragma unroll
  for (int h = 0; h < 12; ++h) acc[h] = 0.f;
  const float4* zr = (const float4*)(zt + jl * 68) + half * 8;
  #pragma unroll
  for (int c4 = 0; c4 < 8; ++c4) {
    float4 zv = zr[c4];
    const float* w0 = wp + (half * 8 + c4) * 48;
    #pragma unroll
    for (int h = 0; h < 12; ++h)
      acc[h] += zv.x * w0[h] + zv.y * w0[12 + h] + zv.z * w0[24 + h] + zv.w * w0[36 + h];
  }
  if (half == 1) {
    #pragma unroll
    for (int h = 0; h < 12; ++h) pl[h * 128 + jl] = acc[h];
  }
  __syncthreads();
  if (half == 0) {
    #pragma unroll
    for (int h = 0; h < 12; ++h)
      alphab[(size_t)h * 262144 + (size_t)i * 512 + j0 + jl] = (acc[h] + pl[h * 128 + jl]) * S3;
  }
}

// ---------------- K2b: logits GEMM + softmax + fused node/vp aggregation + g2l ----------------
// grid 384 = h*32 + it(16 rows); 512 threads (8 waves).
// Phase1: wave ti owns rows {2ti,2ti+1}; full row in registers; 64-lane shfl softmax.
// Phase2: k-split 2 over t8 tiles, double Bt tile, LDS reduce.
__global__ __launch_bounds__(512) void k2b_logits(
    const float* __restrict__ Ac, const float* __restrict__ BcT,
    const float* __restrict__ a2, const float* __restrict__ b2,
    const float* __restrict__ proj, const float* __restrict__ Rg, const float* __restrict__ tg,
    float* __restrict__ alphab, float* __restrict__ featb) {
  int blk = blockIdx.x;
  int h = blk >> 5, i0 = (blk & 31) * 16;
  int tid = threadIdx.x;
  __shared__ float smem[18736];          // 74.9 KB, phase-unioned
  float* At   = smem;                    // [16][60]        phase 1 (0..960)
  float* BtT  = smem + 960;              // [56][132]       phase 1 (960..8352)
  float* b2s  = smem + 8352;             // [512]           phase 1
  float* a2s  = smem + 8864;             // [16]            phase 1 (ends 8880)
  float* als  = smem;                    // [16][516]       phase 2 (0..8256)
  float* Bt2  = smem + 8880;             // [2][64][60]     phase 2 (8880..16560)
  float4* part4 = (float4*)(smem + 16560); // [2][16][14]   phase 2 (16560..18352)
  float* ag   = smem + 18352;            // [16][24]        phase 2 (ends 18736)

  for (int g = tid; g < 224; g += 512) {
    int row = g / 14, u = g % 14;
    *(float4*)(At + row * 60 + u * 4) =
      *(const float4*)(Ac + ((size_t)h * 512 + i0 + row) * 56 + u * 4);
  }
  if (tid < 128) ((float4*)b2s)[tid] = ((const float4*)(b2 + h * 512))[tid];
  if (tid >= 128 && tid < 144) a2s[tid - 128] = a2[h * 512 + i0 + tid - 128];

  int ti = tid >> 6, tj = tid & 63;    // wave ti: rows 2ti, 2ti+1
  int r0 = 2 * ti;
  float lg[2][8];                       // [row][jt*2+u]
  const size_t abase = (size_t)h * 262144;
  for (int jt = 0; jt < 4; ++jt) {
    int j0 = jt * 128;
    __syncthreads();
    for (int g = tid; g < 1792; g += 512) {
      int k = g >> 5, c4 = g & 31;
      *(float4*)(BtT + k * 132 + c4 * 4) =
        *(const float4*)(BcT + ((size_t)h * 56 + k) * 512 + j0 + c4 * 4);
    }
    __syncthreads();
    float a00 = 0.f, a01 = 0.f, a10 = 0.f, a11 = 0.f;
    const float* At0 = At + r0 * 60;
    #pragma unroll 8
    for (int k = 0; k < 56; ++k) {
      float a0 = At0[k], a1 = At0[60 + k];
      float2 b = *(const float2*)(BtT + k * 132 + 2 * tj);
      a00 += a0 * b.x; a01 += a0 * b.y;
      a10 += a1 * b.x; a11 += a1 * b.y;
    }
    int c0 = j0 + 2 * tj;
    const float* prow0 = alphab + abase + (size_t)(i0 + r0) * 512;
    const float* prow1 = prow0 + 512;
    float bb0 = b2s[c0], bb1 = b2s[c0 + 1];
    lg[0][jt*2+0] = a00 + prow0[c0]     + a2s[r0]     + bb0;
    lg[0][jt*2+1] = a01 + prow0[c0 + 1] + a2s[r0]     + bb1;
    lg[1][jt*2+0] = a10 + prow1[c0]     + a2s[r0 + 1] + bb0;
    lg[1][jt*2+1] = a11 + prow1[c0 + 1] + a2s[r0 + 1] + bb1;
  }
  __syncthreads();   // all At/BtT/b2s reads done before als overwrites
  // --- softmax per row (full 64-lane wave owns the row) ---
  #pragma unroll
  for (int r = 0; r < 2; ++r) {
    float m = lg[r][0];
    #pragma unroll
    for (int u = 1; u < 8; ++u) m = fmaxf(m, lg[r][u]);
    #pragma unroll
    for (int s = 32; s > 0; s >>= 1) m = fmaxf(m, __shfl_xor(m, s));
    float ssum = 0.f;
    #pragma unroll
    for (int u = 0; u < 8; ++u) { lg[r][u] = __expf(lg[r][u] - m); ssum += lg[r][u]; }
    #pragma unroll
    for (int s = 32; s > 0; s >>= 1) ssum += __shfl_xor(ssum, s);
    float inv = 1.0f / ssum;
    int row = r0 + r;
    float* orow = alphab + abase + (size_t)(i0 + row) * 512;
    #pragma unroll
    for (int jt = 0; jt < 4; ++jt) {
      float2 v = make_float2(lg[r][jt*2+0] * inv, lg[r][jt*2+1] * inv);
      *(float2*)(orow + jt * 128 + 2 * tj) = v;
      *(float2*)(als + row * 516 + jt * 128 + 2 * tj) = v;
    }
  }
  // --- phase 2: node/vp aggregation, k-split 2, double Bt tile ---
  int half = tid / 224, rem = tid % 224;   // half 0,1 valid; tid>=448 idle
  int rg = rem / 14, cgp = rem % 14;
  int c0p = cgp * 4;
  float4 acc4 = {0,0,0,0};
  for (int tt = 0; tt < 4; ++tt) {
    __syncthreads();
    for (int g = tid; g < 1792; g += 512) {
      int hh = g / 896, gg = g % 896;
      int row = gg / 14, u = gg % 14;
      const float* pr = proj + (size_t)((tt + 4 * hh) * 64 + row) * PCOLS;
      float4 vv = (u < 8) ? *(const float4*)(&pr[1344 + h * 32 + u * 4])
                          : *(const float4*)(&pr[1728 + h * 24 + (u - 8) * 4]);
      int dst = (u < 8) ? u * 4 : 32 + (u - 8) * 4;
      *(float4*)(Bt2 + hh * 3840 + row * 60 + dst) = vv;
    }
    __syncthreads();
    if (tid < 448) {
      const float* arow = als + rg * 516 + (tt + 4 * half) * 64;
      const float* bt = Bt2 + half * 3840;
      #pragma unroll 8
      for (int kk = 0; kk < 64; ++kk) {
        float a = arow[kk];
        float4 b = *(const float4*)(bt + kk * 60 + c0p);
        FMA4(acc4, a, b);
      }
    }
  }
  __syncthreads();
  if (tid < 448) part4[half * 224 + rg * 14 + cgp] = acc4;
  __syncthreads();
  if (tid < 224) {
    float4 s = part4[rem];
    float4 s2 = part4[224 + rem];
    ADD4(s, s2);
    if (c0p < 32) {
      *(float4*)(&featb[(size_t)(i0 + rg) * 1440 + 768 + h * 32 + c0p]) = s;
    } else {
      int cc = c0p - 32;
      ag[rg * 24 + cc + 0] = s.x; ag[rg * 24 + cc + 1] = s.y;
      ag[rg * 24 + cc + 2] = s.z; ag[rg * 24 + cc + 3] = s.w;
    }
  }
  __syncthreads();
  if (tid < 128) {   // g2l: 16 rows x 8 points
    int row = tid >> 3, p = tid & 7;
    const float* R  = Rg + (size_t)(i0 + row) * 9;
    const float* tt = tg + (size_t)(i0 + row) * 3;
    float d0 = ag[row * 24 + p * 3 + 0] - tt[0];
    float d1 = ag[row * 24 + p * 3 + 1] - tt[1];
    float d2 = ag[row * 24 + p * 3 + 2] - tt[2];
    float* o = featb + (size_t)(i0 + row) * 1440 + 1152 + h * 24 + p * 3;
    o[0] = R[0]*d0 + R[3]*d1 + R[6]*d2;
    o[1] = R[1]*d0 + R[4]*d1 + R[7]*d2;
    o[2] = R[2]*d0 + R[5]*d1 + R[8]*d2;
  }
}

// ---------------- K3a: feat_p2n = alpha[h][i][:] @ z[i] (512x64) ----------------
__global__ __launch_bounds__(256) void k3a_p2n(
    const float* __restrict__ alphab, const float* __restrict__ z,
    float* __restrict__ featb) {
  int i = blockIdx.x, tid = threadIdx.x;
  __shared__ float al[12 * 516];
  __shared__ float zt[64 * 68];
  for (int g = tid; g < 1536; g += 256) {
    int row = g >> 7, c4 = g & 127;
    *(float4*)(al + row * 516 + c4 * 4) =
      *(const float4*)(alphab + (size_t)row * 262144 + (size_t)i * 512 + c4 * 4);
  }
  int h = tid >> 4, c4 = tid & 15;
  float4 acc = {0.f, 0.f, 0.f, 0.f};
  const float4* zsrc = (const float4*)(z + (size_t)i * 512 * 64);
  for (int t8 = 0; t8 < 8; ++t8) {
    __syncthreads();
    for (int g = tid; g < 1024; g += 256) {
      int row = g >> 4, cc = g & 15;
      *(float4*)(&zt[row * 68 + cc * 4]) = zsrc[(t8 * 64 + row) * 16 + cc];
    }
    __syncthreads();
    if (tid < 192) {
      const float* ar = al + h * 516 + t8 * 64;
      #pragma unroll
      for (int k4 = 0; k4 < 16; ++k4) {
        float4 a4 = *(const float4*)(&ar[k4 * 4]);
        float4 z0 = *(const float4*)(&zt[(k4*4+0) * 68 + c4 * 4]);
        float4 z1 = *(const float4*)(&zt[(k4*4+1) * 68 + c4 * 4]);
        float4 z2 = *(const float4*)(&zt[(k4*4+2) * 68 + c4 * 4]);
        float4 z3 = *(const float4*)(&zt[(k4*4+3) * 68 + c4 * 4]);
        FMA4(acc, a4.x, z0); FMA4(acc, a4.y, z1); FMA4(acc, a4.z, z2); FMA4(acc, a4.w, z3);
      }
    }
  }
  if (tid < 192)
    *(float4*)(&featb[(size_t)i * 1440 + h * 64 + c4 * 4]) = acc;
}

// ---------------- K4: Wo GEMM + LN1 + MLP + LN2 ----------------
__global__ __launch_bounds__(512) void k4_mlp(
    const float* __restrict__ featb, const float* __restrict__ x,
    const float* __restrict__ Wo, const float* __restrict__ bo,
    const float* __restrict__ ln1s, const float* __restrict__ ln1o,
    const float* __restrict__ W1, const float* __restrict__ b1,
    const float* __restrict__ W2, const float* __restrict__ b2,
    const float* __restrict__ W3, const float* __restrict__ b3,
    const float* __restrict__ ln2s, const float* __restrict__ ln2o,
    float* __restrict__ out) {
  int i0 = blockIdx.x * 2;
  int tid = threadIdx.x;
  __shared__ float fs[2 * 1440];
  __shared__ float4 part4[16][2][32];
  __shared__ float stgA[2][128], stgB[2][128], stgC[2][128];
  for (int g = tid; g < 720; g += 512)
    ((float4*)fs)[g] = ((const float4*)(featb + (size_t)i0 * 1440))[g];
  __syncthreads();
  int q = tid >> 5, cg = tid & 31;
  {
    float4 a0 = {0,0,0,0}, a1 = {0,0,0,0};
    int cb = q * 90;
    const float* f0 = fs + cb, *f1 = fs + 1440 + cb;
    #pragma unroll 6
    for (int c = 0; c < 90; ++c) {
      float4 w = *((const float4*)(Wo + (size_t)(cb + c) * 128) + cg);
      FMA4(a0, f0[c], w);
      FMA4(a1, f1[c], w);
    }
    part4[q][0][cg] = a0;
    part4[q][1][cg] = a1;
  }
  __syncthreads();
  if (tid < 64) {
    int rr = tid >> 5, c = tid & 31;
    float4 s = part4[0][rr][c];
    #pragma unroll
    for (int k = 1; k < 16; ++k) ADD4(s, part4[k][rr][c]);
    float4 bo4 = ((const float4*)bo)[c];
    float4 xr4 = ((const float4*)(x + (size_t)(i0 + rr) * 128))[c];
    s.x += bo4.x + xr4.x; s.y += bo4.y + xr4.y; s.z += bo4.z + xr4.z; s.w += bo4.w + xr4.w;
    ((float4*)stgA[rr])[c] = s;
  }
  __syncthreads();
  int q2 = tid >> 7, col = tid & 127, rr = q2 & 1;
  float x1;
  {
    float y = stgA[rr][col];
    float s1 = 0.f, s2 = 0.f;
    #pragma unroll 8
    for (int c4 = 0; c4 < 32; ++c4) {
      float4 v = ((const float4*)stgA[rr])[c4];
      s1 += v.x + v.y + v.z + v.w;
      s2 += v.x*v.x + v.y*v.y + v.z*v.z + v.w*v.w;
    }
    float mu = s1 * (1.f / 128.f);
    float var = s2 * (1.f / 128.f) - mu * mu;
    x1 = (y - mu) * rsqrtf(var + 1e-5f) * ln1s[col] + ln1o[col];
  }
  __syncthreads();
  stgB[rr][col] = x1;
  __syncthreads();
  int sub = tid >> 5, rr1 = sub & 1, kq = sub >> 1;
  {
    float4 aa = {0,0,0,0};
    int c0 = kq * 16;
    #pragma unroll
    for (int c = 0; c < 16; ++c) {
      float4 w = *((const float4*)(W1 + (size_t)(c0 + c) * 128) + cg);
      FMA4(aa, stgB[rr1][c0 + c], w);
    }
    part4[sub][0][cg] = aa;
  }
  __syncthreads();
  if (tid < 64) {
    int r2 = tid >> 5, c = tid & 31;
    float4 s = part4[r2][0][c];
    #pragma unroll
    for (int k = 1; k < 8; ++k) ADD4(s, part4[k * 2 + r2][0][c]);
    float4 b4 = ((const float4*)b1)[c];
    s.x = fmaxf(s.x + b4.x, 0.f); s.y = fmaxf(s.y + b4.y, 0.f);
    s.z = fmaxf(s.z + b4.z, 0.f); s.w = fmaxf(s.w + b4.w, 0.f);
    ((float4*)stgA[r2])[c] = s;
  }
  __syncthreads();
  {
    float4 aa = {0,0,0,0};
    int c0 = kq * 16;
    #pragma unroll
    for (int c = 0; c < 16; ++c) {
      float4 w = *((const float4*)(W2 + (size_t)(c0 + c) * 128) + cg);
      FMA4(aa, stgA[rr1][c0 + c], w);
    }
    part4[sub][0][cg] = aa;
  }
  __syncthreads();
  if (tid < 64) {
    int r2 = tid >> 5, c = tid & 31;
    float4 s = part4[r2][0][c];
    #pragma unroll
    for (int k = 1; k < 8; ++k) ADD4(s, part4[k * 2 + r2][0][c]);
    float4 b4 = ((const float4*)b2)[c];
    s.x = fmaxf(s.x + b4.x, 0.f); s.y = fmaxf(s.y + b4.y, 0.f);
    s.z = fmaxf(s.z + b4.z, 0.f); s.w = fmaxf(s.w + b4.w, 0.f);
    ((float4*)stgC[r2])[c] = s;
  }
  __syncthreads();
  {
    float4 aa = {0,0,0,0};
    int c0 = kq * 16;
    #pragma unroll
    for (int c = 0; c < 16; ++c) {
      float4 w = *((const float4*)(W3 + (size_t)(c0 + c) * 128) + cg);
      FMA4(aa, stgC[rr1][c0 + c], w);
    }
    part4[sub][0][cg] = aa;
  }
  __syncthreads();
  if (tid < 64) {
    int r2 = tid >> 5, c = tid & 31;
    float4 s = part4[r2][0][c];
    #pragma unroll
    for (int k = 1; k < 8; ++k) ADD4(s, part4[k * 2 + r2][0][c]);
    float4 b4 = ((const float4*)b3)[c];
    s.x += b4.x; s.y += b4.y; s.z += b4.z; s.w += b4.w;
    ((float4*)stgA[r2])[c] = s;
  }
  __syncthreads();
  {
    float y2 = x1 + stgA[rr][col];
    stgC[rr][col] = y2;
    __syncthreads();
    float s1 = 0.f, s2 = 0.f;
    #pragma unroll 8
    for (int c4 = 0; c4 < 32; ++c4) {
      float4 v = ((const float4*)stgC[rr])[c4];
      s1 += v.x + v.y + v.z + v.w;
      s2 += v.x*v.x + v.y*v.y + v.z*v.z + v.w*v.w;
    }
    float mu = s1 * (1.f / 128.f);
    float var = s2 * (1.f / 128.f) - mu * mu;
    if (q2 < 2)
      out[(size_t)(i0 + rr) * 128 + col] = (y2 - mu) * rsqrtf(var + 1e-5f) * ln2s[col] + ln2o[col];
  }
}

// ---------------- launch ----------------
extern "C" void kernel_launch(void* const* d_in, const int* in_sizes, int n_in,
                              void* d_out, int out_size, void* d_ws, size_t ws_size,
                              hipStream_t stream) {
  const float* Rg   = (const float*)d_in[0];
  const float* tg   = (const float*)d_in[1];
  const float* x    = (const float*)d_in[2];
  const float* z    = (const float*)d_in[3];
  // d_in[4] = mask (all true) -> no-op
  const float* Wq   = (const float*)d_in[5];
  const float* Wk   = (const float*)d_in[6];
  const float* Wpair= (const float*)d_in[7];
  const float* Wqp  = (const float*)d_in[8];
  const float* Wkp  = (const float*)d_in[9];
  const float* Wv   = (const float*)d_in[10];
  const float* Wvp  = (const float*)d_in[11];
  const float* sc   = (const float*)d_in[12];
  const float* Wo   = (const float*)d_in[13];
  const float* bo   = (const float*)d_in[14];
  const float* ln1s = (const float*)d_in[15];
  const float* ln1o = (const float*)d_in[16];
  const float* W1   = (const float*)d_in[17];
  const float* b1   = (const float*)d_in[18];
  const float* W2   = (const float*)d_in[19];
  const float* b2   = (const float*)d_in[20];
  const float* W3   = (const float*)d_in[21];
  const float* b3   = (const float*)d_in[22];
  const float* ln2s = (const float*)d_in[23];
  const float* ln2o = (const float*)d_in[24];

  float* ws = (float*)d_ws;
  float* proj   = ws;                        // 512*2016
  float* Ac     = proj + 512 * 2016;         // 12*512*56
  float* BcT    = Ac + 344064;               // 12*56*512
  float* a2     = BcT + 344064;
  float* b2v    = a2 + 6144;
  float* alphab = b2v + 6144;                // 12*512*512
  float* featb  = alphab + 3145728;          // 512*1440

  k1_gemm  <<<168, 384, 0, stream>>>(x, Wq, Wk, Wqp, Wkp, Wv, Wvp, proj);
  k1b_prep <<<512, 256, 0, stream>>>(Rg, tg, sc, proj, Ac, BcT, a2, b2v);
  k2a_pair <<<2048, 256, 0, stream>>>(z, Wpair, alphab);
  k2b_logits<<<384, 512, 0, stream>>>(Ac, BcT, a2, b2v, proj, Rg, tg, alphab, featb);
  k3a_p2n  <<<512, 256, 0, stream>>>(alphab, z, featb);
  k4_mlp   <<<256, 512, 0, stream>>>(featb, x, Wo, bo, ln1s, ln1o,
                                     W1, b1, W2, b2, W3, b3, ln2s, ln2o, (float*)d_out);
}